// Round 2
// baseline (1247.064 us; speedup 1.0000x reference)
//
#include <hip/hip_runtime.h>

#define NEG_SLOPE 0.2f

typedef unsigned short ushort_t;
typedef unsigned int uint_t;
typedef __attribute__((ext_vector_type(8))) short bf16x8;   // 8 bf16 in 4 VGPRs
typedef __attribute__((ext_vector_type(4))) float f32x4;

__device__ inline float bf2f(ushort_t u) { union { uint_t i; float f; } v; v.i = ((uint_t)u) << 16; return v.f; }
__device__ inline ushort_t f2bf(float f) {
    union { float f; uint_t u; } v; v.f = f;
    uint_t r = v.u + 0x7fffu + ((v.u >> 16) & 1u);
    return (ushort_t)(r >> 16);
}
__device__ inline float2 up2(uint_t w) { return make_float2(bf2f((ushort_t)(w & 0xFFFFu)), bf2f((ushort_t)(w >> 16))); }
// float atomic max via int ordering trick (init must be -inf)
__device__ inline void atomicMaxF(float* addr, float val) {
    if (val >= 0.0f) atomicMax((int*)addr, __float_as_int(val));
    else             atomicMin((uint_t*)addr, __float_as_uint(val));
}
// dtype-flexible loads (bf=1: buffer holds bf16; bf=0: fp32)
__device__ inline float ld_f(const void* p, size_t i, int bf) { return bf ? bf2f(((const ushort_t*)p)[i]) : ((const float*)p)[i]; }
__device__ inline ushort_t ld_b(const void* p, size_t i, int bf) { return bf ? ((const ushort_t*)p)[i] : f2bf(((const float*)p)[i]); }
// edge fetch with int64/int32 handling; self-loops appended at e >= E_in
__device__ inline void edge_sd(const int* __restrict__ ei, int e, int E_in, int i64, int& src, int& dst) {
    if (e < E_in) {
        if (i64) { src = ei[2 * (size_t)e]; dst = ei[2 * ((size_t)E_in + e)]; }
        else     { src = ei[e];             dst = ei[(size_t)E_in + e]; }
    } else { src = dst = e - E_in; }
}

// ---------------- dtype detection ----------------
// flags[0]=1 if float buffers are bf16-packed; flags[1]=1 if edge_index is int64
__global__ void k_detect(const uint_t* __restrict__ xw, const int* __restrict__ ei, int* flags) {
    __shared__ int cnt;
    if (threadIdx.x == 0) cnt = 0;
    __syncthreads();
    uint_t w = xw[threadIdx.x];           // 256 words of x
    int eb = (int)((w >> 7) & 0xFFu);     // low-half bf16 exponent field
    if (eb >= 113 && eb <= 142) atomicAdd(&cnt, 1);
    __syncthreads();
    if (threadIdx.x == 0) {
        flags[0] = (cnt > 128) ? 1 : 0;
        int z = 0;
        #pragma unroll
        for (int i = 1; i < 16; i += 2) z += (ei[i] == 0) ? 1 : 0;  // int64 high words
        flags[1] = (z == 8) ? 1 : 0;
    }
}

// ---------------- input normalization ----------------
__global__ void k_cvt_x(const void* __restrict__ x, ushort_t* __restrict__ xb, int n, const int* flags) {
    int i = blockIdx.x * blockDim.x + threadIdx.x;
    if (i < n) xb[i] = ld_b(x, i, flags[0]);
}

__global__ void k_cvt_params(const void* Wl1, const void* Wr1, const void* att1, const void* b1,
                             const void* Wl2, const void* Wr2, const void* att2, const void* b2,
                             const void* Wo, const void* bo,
                             ushort_t* Wl1b, ushort_t* Wr1b, ushort_t* Wl2b, ushort_t* Wr2b,
                             float* att1f, float* b1f, float* att2f, float* b2f, float* Wof, float* bof,
                             int sW1, int sW2, int satt1, int sb1, int satt2, int sb2, int sWo, int sbo,
                             const int* flags) {
    int i = blockIdx.x * blockDim.x + threadIdx.x;
    int bf = flags[0];
    if (i < sW1) { Wl1b[i] = ld_b(Wl1, i, bf); Wr1b[i] = ld_b(Wr1, i, bf); }
    if (i < sW2) { Wl2b[i] = ld_b(Wl2, i, bf); Wr2b[i] = ld_b(Wr2, i, bf); }
    if (i < satt1) att1f[i] = ld_f(att1, i, bf);
    if (i < sb1)   b1f[i]   = ld_f(b1, i, bf);
    if (i < satt2) att2f[i] = ld_f(att2, i, bf);
    if (i < sb2)   b2f[i]   = ld_f(b2, i, bf);
    if (i < sWo)   Wof[i]   = ld_f(Wo, i, bf);
    if (i < sbo)   bof[i]   = ld_f(bo, i, bf);
}

// ---------------- init: -inf maxes, zero degrees ----------------
__global__ void k_init(float* mx1, float* mx2, int* deg, int n4, int n) {
    int i = blockIdx.x * blockDim.x + threadIdx.x;
    if (i < n4) { mx1[i] = -__builtin_inff(); mx2[i] = -__builtin_inff(); }
    if (i < n)  deg[i] = 0;
}

// ---------------- CSR build over dst ----------------
__global__ void k_count(const int* __restrict__ ei, int E_in, int Etot, const int* flags, int* deg) {
    int e = blockIdx.x * blockDim.x + threadIdx.x;
    if (e >= Etot) return;
    int src, dst; edge_sd(ei, e, E_in, flags[1], src, dst);
    atomicAdd(&deg[dst], 1);
}

__global__ void k_scan(const int* __restrict__ deg, int* offs, int* cursor, int n) {
    __shared__ int sh[1024];
    int t = threadIdx.x;
    int chunk = (n + 1023) / 1024;
    int s = t * chunk, e = min(s + chunk, n);
    int local = 0;
    for (int i = s; i < e; i++) local += deg[i];
    sh[t] = local; __syncthreads();
    for (int off = 1; off < 1024; off <<= 1) {
        int v = (t >= off) ? sh[t - off] : 0;
        __syncthreads();
        sh[t] += v; __syncthreads();
    }
    int run = sh[t] - local;   // exclusive base
    for (int i = s; i < e; i++) { offs[i] = run; cursor[i] = run; run += deg[i]; }
    if (e == n) offs[n] = run;
}

__global__ void k_fill(const int* __restrict__ ei, int E_in, int Etot, const int* flags,
                       int* cursor, int* s_eid, int* s_src) {
    int e = blockIdx.x * blockDim.x + threadIdx.x;
    if (e >= Etot) return;
    int src, dst; edge_sd(ei, e, E_in, flags[1], src, dst);
    int p = atomicAdd(&cursor[dst], 1);
    s_eid[p] = e; s_src[p] = src;
}

// ------- MFMA GEMM: Y[M,NOUT](bf16) = X[M,128](bf16) @ W[128,NOUT](bf16) -------
template <int NOUT>
__global__ __launch_bounds__(256) void k_gemm(const ushort_t* __restrict__ X,
                                              const ushort_t* __restrict__ W,
                                              ushort_t* __restrict__ Y, int M) {
    const int lane = threadIdx.x & 63, wid = threadIdx.x >> 6;
    const int ntiles = M >> 4;
    int rt = blockIdx.x * 4 + wid;
    if (rt >= ntiles) return;
    const int colbase = blockIdx.y * 64;
    const int quad = lane >> 4, lo = lane & 15;

    bf16x8 bfr[4][4];  // B[k=quad*8+j][n=colbase+nt*16+lo]
    #pragma unroll
    for (int nt = 0; nt < 4; nt++) {
        int n = colbase + nt * 16 + lo;
        #pragma unroll
        for (int kc = 0; kc < 4; kc++) {
            int kb = kc * 32 + quad * 8;
            bf16x8 b;
            #pragma unroll
            for (int j = 0; j < 8; j++) b[j] = (short)W[(size_t)(kb + j) * NOUT + n];
            bfr[nt][kc] = b;
        }
    }

    f32x4 acc[4];
    #pragma unroll
    for (int nt = 0; nt < 4; nt++) acc[nt] = (f32x4){0.f, 0.f, 0.f, 0.f};

    int r = rt * 16 + lo;
    const ushort_t* xrow = X + (size_t)r * 128 + quad * 8;
    #pragma unroll
    for (int kc = 0; kc < 4; kc++) {
        bf16x8 a = *(const bf16x8*)(xrow + kc * 32);   // 16B aligned
        #pragma unroll
        for (int nt = 0; nt < 4; nt++)
            acc[nt] = __builtin_amdgcn_mfma_f32_16x16x32_bf16(a, bfr[nt][kc], acc[nt], 0, 0, 0);
    }
    // C/D: col = lane&15, row = quad*4 + reg  [m89-verified]
    #pragma unroll
    for (int nt = 0; nt < 4; nt++) {
        int col = colbase + nt * 16 + lo;
        #pragma unroll
        for (int ri = 0; ri < 4; ri++) {
            int row = rt * 16 + quad * 4 + ri;
            Y[(size_t)row * NOUT + col] = f2bf(acc[nt][ri]);
        }
    }
}

// ---------------- layer 1 e-scores: thread per (edge, head), C=32 ----------------
__global__ void k_e1(const ushort_t* __restrict__ xl, const ushort_t* __restrict__ xr,
                     const int* __restrict__ ei, const float* __restrict__ att,
                     int E_in, int Etot, const int* flags, float* e1, float* mx) {
    int t = blockIdx.x * blockDim.x + threadIdx.x;
    if (t >= Etot * 4) return;
    int e = t >> 2, h = t & 3;
    int src, dst; edge_sd(ei, e, E_in, flags[1], src, dst);
    const uint4* pl = (const uint4*)(xl + (size_t)src * 128 + h * 32);
    const uint4* pr = (const uint4*)(xr + (size_t)dst * 128 + h * 32);
    const float* ap = att + h * 32;
    float acc = 0.f;
    #pragma unroll
    for (int q = 0; q < 4; q++) {
        uint4 a = pl[q], b = pr[q];
        uint_t aw[4] = {a.x, a.y, a.z, a.w}, bw[4] = {b.x, b.y, b.z, b.w};
        #pragma unroll
        for (int j = 0; j < 4; j++) {
            float2 av = up2(aw[j]), bv = up2(bw[j]);
            float m0 = av.x + bv.x, m1 = av.y + bv.y;
            m0 = m0 > 0.f ? m0 : NEG_SLOPE * m0;
            m1 = m1 > 0.f ? m1 : NEG_SLOPE * m1;
            acc += m0 * ap[q * 8 + 2 * j] + m1 * ap[q * 8 + 2 * j + 1];
        }
    }
    e1[(size_t)e * 4 + h] = acc;
    atomicMaxF(&mx[(size_t)dst * 4 + h], acc);
}

// ------- layer 1 gather-aggregate + bias + relu -> h1 (bf16); wave per node -------
__global__ __launch_bounds__(256) void k_agg1(const ushort_t* __restrict__ xl,
                                              const float* __restrict__ e1,
                                              const float* __restrict__ mx,
                                              const int* __restrict__ offs,
                                              const int* __restrict__ s_eid,
                                              const int* __restrict__ s_src,
                                              const float* __restrict__ b1,
                                              int n, ushort_t* __restrict__ h1) {
    int lane = threadIdx.x & 63, wid = threadIdx.x >> 6;
    int node = blockIdx.x * 4 + wid;
    if (node >= n) return;
    int h = lane >> 4;
    float m = mx[(size_t)node * 4 + h];
    int o0 = offs[node], o1 = offs[node + 1];
    float s = 0.f, a0 = 0.f, a1 = 0.f;
    for (int i = o0; i < o1; i++) {
        int eid = s_eid[i], src = s_src[i];
        float w = __expf(e1[(size_t)eid * 4 + h] - m);
        s += w;
        float2 v = up2(*(const uint_t*)(xl + (size_t)src * 128 + 2 * lane));
        a0 += w * v.x; a1 += w * v.y;
    }
    float inv = 1.f / s;
    float r0 = fmaxf(a0 * inv + b1[2 * lane],     0.f);
    float r1 = fmaxf(a1 * inv + b1[2 * lane + 1], 0.f);
    uint_t pack = (uint_t)f2bf(r0) | ((uint_t)f2bf(r1) << 16);
    *(uint_t*)(h1 + (size_t)node * 128 + 2 * lane) = pack;
}

// ---------------- layer 2 e-scores: 4 waves (heads) per edge, C=128 ----------------
__global__ __launch_bounds__(256) void k_e2(const ushort_t* __restrict__ xl,
                                            const ushort_t* __restrict__ xr,
                                            const int* __restrict__ ei,
                                            const float* __restrict__ att,
                                            int E_in, int Etot, const int* flags,
                                            float* e2, float* mx) {
    int h = threadIdx.x >> 6, lane = threadIdx.x & 63;
    int i64 = flags[1];
    for (int e = blockIdx.x; e < Etot; e += gridDim.x) {
        int src, dst; edge_sd(ei, e, E_in, i64, src, dst);
        float2 a = up2(*(const uint_t*)(xl + (size_t)src * 512 + h * 128 + 2 * lane));
        float2 b = up2(*(const uint_t*)(xr + (size_t)dst * 512 + h * 128 + 2 * lane));
        float m0 = a.x + b.x, m1 = a.y + b.y;
        m0 = m0 > 0.f ? m0 : NEG_SLOPE * m0;
        m1 = m1 > 0.f ? m1 : NEG_SLOPE * m1;
        float v = m0 * att[h * 128 + 2 * lane] + m1 * att[h * 128 + 2 * lane + 1];
        #pragma unroll
        for (int o = 32; o > 0; o >>= 1) v += __shfl_xor(v, o, 64);
        if (lane == 0) {
            e2[(size_t)e * 4 + h] = v;
            atomicMaxF(&mx[(size_t)dst * 4 + h], v);
        }
    }
}

// ---- layer 2 aggregate (mean heads) + b2 -> h ; fused decoder; dtype-branched out ----
__global__ __launch_bounds__(256) void k_agg2(const ushort_t* __restrict__ xl,
                                              const float* __restrict__ e2,
                                              const float* __restrict__ mx,
                                              const int* __restrict__ offs,
                                              const int* __restrict__ s_eid,
                                              const int* __restrict__ s_src,
                                              const float* __restrict__ b2,
                                              const float* __restrict__ Wo,
                                              const float* __restrict__ bo,
                                              int n, const int* flags, void* dout) {
    __shared__ float part[4][128];
    __shared__ float hbuf[128];
    int node = blockIdx.x;
    int h = threadIdx.x >> 6, lane = threadIdx.x & 63;
    float m = mx[(size_t)node * 4 + h];
    int o0 = offs[node], o1 = offs[node + 1];
    float s = 0.f, a0 = 0.f, a1 = 0.f;
    for (int i = o0; i < o1; i++) {
        int eid = s_eid[i], src = s_src[i];
        float w = __expf(e2[(size_t)eid * 4 + h] - m);
        s += w;
        float2 v = up2(*(const uint_t*)(xl + (size_t)src * 512 + h * 128 + 2 * lane));
        a0 += w * v.x; a1 += w * v.y;
    }
    float inv = 1.f / s;
    part[h][2 * lane]     = a0 * inv;
    part[h][2 * lane + 1] = a1 * inv;
    __syncthreads();
    int t = threadIdx.x;
    int bf = flags[0];
    if (t < 128) {
        float hm = 0.25f * (part[0][t] + part[1][t] + part[2][t] + part[3][t]) + b2[t];
        hbuf[t] = hm;
        size_t oidx = (size_t)n * 2 + (size_t)node * 128 + t;
        if (bf) ((ushort_t*)dout)[oidx] = f2bf(hm);
        else    ((float*)dout)[oidx]    = hm;
    }
    __syncthreads();
    if (h < 2) {  // decoder: out[node,h] = dot(hbuf, Wo[:,h]) + bo[h]
        float v = hbuf[lane] * Wo[lane * 2 + h] + hbuf[lane + 64] * Wo[(lane + 64) * 2 + h];
        #pragma unroll
        for (int o = 32; o > 0; o >>= 1) v += __shfl_xor(v, o, 64);
        if (lane == 0) {
            float r = v + bo[h];
            size_t oidx = (size_t)node * 2 + h;
            if (bf) ((ushort_t*)dout)[oidx] = f2bf(r);
            else    ((float*)dout)[oidx]    = r;
        }
    }
}

extern "C" void kernel_launch(void* const* d_in, const int* in_sizes, int n_in,
                              void* d_out, int out_size, void* d_ws, size_t ws_size,
                              hipStream_t stream) {
    const void* x    = d_in[0];
    const int*  ei   = (const int*)d_in[1];
    const void* Wl1  = d_in[2];
    const void* Wr1  = d_in[3];
    const void* att1 = d_in[4];
    const void* b1   = d_in[5];
    const void* Wl2  = d_in[6];
    const void* Wr2  = d_in[7];
    const void* att2 = d_in[8];
    const void* b2   = d_in[9];
    const void* Wo   = d_in[10];
    const void* bo   = d_in[11];

    const int N    = in_sizes[0] / 128;   // 50000
    const int E_in = in_sizes[1] / 2;     // 800000 (element count same for i32/i64)
    const int Etot = E_in + N;

    const int sW1 = in_sizes[2], sW2 = in_sizes[6];
    const int satt1 = in_sizes[4], sb1 = in_sizes[5];
    const int satt2 = in_sizes[8], sb2 = in_sizes[9];
    const int sWo = in_sizes[10], sbo = in_sizes[11];

    char* w = (char*)d_ws;
    size_t off = 0;
    auto take = [&](size_t bytes) -> void* {
        void* p = w + off;
        off += (bytes + 255) & ~(size_t)255;
        return p;
    };
    int*      flags  = (int*)take(256);
    ushort_t* xb     = (ushort_t*)take((size_t)N * 128 * sizeof(ushort_t));
    ushort_t* Wl1b   = (ushort_t*)take((size_t)sW1 * 2);
    ushort_t* Wr1b   = (ushort_t*)take((size_t)sW1 * 2);
    ushort_t* Wl2b   = (ushort_t*)take((size_t)sW2 * 2);
    ushort_t* Wr2b   = (ushort_t*)take((size_t)sW2 * 2);
    float*    att1f  = (float*)take((size_t)satt1 * 4);
    float*    b1f    = (float*)take((size_t)sb1 * 4);
    float*    att2f  = (float*)take((size_t)satt2 * 4);
    float*    b2f    = (float*)take((size_t)sb2 * 4);
    float*    Wof    = (float*)take((size_t)sWo * 4);
    float*    bof    = (float*)take((size_t)sbo * 4);
    float*    e_buf  = (float*)take((size_t)Etot * 4 * sizeof(float));  // shared layer1/2
    float*    mx1    = (float*)take((size_t)N * 4 * sizeof(float));
    float*    mx2    = (float*)take((size_t)N * 4 * sizeof(float));
    int*      deg    = (int*)take((size_t)N * sizeof(int));
    int*      offs   = (int*)take((size_t)(N + 1) * sizeof(int));
    int*      cursor = (int*)take((size_t)(N + 1) * sizeof(int));
    int*      s_eid  = (int*)take((size_t)Etot * sizeof(int));
    int*      s_src  = (int*)take((size_t)Etot * sizeof(int));
    ushort_t* h1     = (ushort_t*)take((size_t)N * 128 * sizeof(ushort_t));
    ushort_t* xl1b   = (ushort_t*)take((size_t)N * 128 * sizeof(ushort_t));
    ushort_t* xr1b   = (ushort_t*)take((size_t)N * 128 * sizeof(ushort_t));
    ushort_t* xl2b   = (ushort_t*)take((size_t)N * 512 * sizeof(ushort_t));
    ushort_t* xr2b   = (ushort_t*)take((size_t)N * 512 * sizeof(ushort_t));

    dim3 b256(256);
    k_detect<<<1, b256, 0, stream>>>((const uint_t*)x, ei, flags);
    k_cvt_x<<<(N * 128 + 255) / 256, b256, 0, stream>>>(x, xb, N * 128, flags);
    k_cvt_params<<<(sW2 + 255) / 256, b256, 0, stream>>>(
        Wl1, Wr1, att1, b1, Wl2, Wr2, att2, b2, Wo, bo,
        Wl1b, Wr1b, Wl2b, Wr2b, att1f, b1f, att2f, b2f, Wof, bof,
        sW1, sW2, satt1, sb1, satt2, sb2, sWo, sbo, flags);

    int n4 = N * 4;
    k_init<<<(n4 + 255) / 256, b256, 0, stream>>>(mx1, mx2, deg, n4, N);
    k_count<<<(Etot + 255) / 256, b256, 0, stream>>>(ei, E_in, Etot, flags, deg);
    k_scan<<<1, 1024, 0, stream>>>(deg, offs, cursor, N);
    k_fill<<<(Etot + 255) / 256, b256, 0, stream>>>(ei, E_in, Etot, flags, cursor, s_eid, s_src);

    dim3 g1((N / 16 + 3) / 4, 128 / 64);
    k_gemm<128><<<g1, b256, 0, stream>>>(xb, Wl1b, xl1b, N);
    k_gemm<128><<<g1, b256, 0, stream>>>(xb, Wr1b, xr1b, N);
    k_e1<<<(Etot * 4 + 255) / 256, b256, 0, stream>>>(xl1b, xr1b, ei, att1f, E_in, Etot, flags, e_buf, mx1);
    k_agg1<<<(N + 3) / 4, b256, 0, stream>>>(xl1b, e_buf, mx1, offs, s_eid, s_src, b1f, N, h1);

    dim3 g2((N / 16 + 3) / 4, 512 / 64);
    k_gemm<512><<<g2, b256, 0, stream>>>(h1, Wl2b, xl2b, N);
    k_gemm<512><<<g2, b256, 0, stream>>>(h1, Wr2b, xr2b, N);
    k_e2<<<16384, b256, 0, stream>>>(xl2b, xr2b, ei, att2f, E_in, Etot, flags, e_buf, mx2);

    k_agg2<<<N, b256, 0, stream>>>(xl2b, e_buf, mx2, offs, s_eid, s_src,
                                   b2f, Wof, bof, N, flags, d_out);
}

// Round 3
// 843.154 us; speedup vs baseline: 1.4790x; 1.4790x over previous
//
#include <hip/hip_runtime.h>

#define NEG_SLOPE 0.2f

typedef unsigned short ushort_t;
typedef unsigned int uint_t;
typedef __attribute__((ext_vector_type(8))) short bf16x8;   // 8 bf16 in 4 VGPRs
typedef __attribute__((ext_vector_type(4))) float f32x4;

__device__ inline float bf2f(ushort_t u) { union { uint_t i; float f; } v; v.i = ((uint_t)u) << 16; return v.f; }
__device__ inline ushort_t f2bf(float f) {
    union { float f; uint_t u; } v; v.f = f;
    uint_t r = v.u + 0x7fffu + ((v.u >> 16) & 1u);
    return (ushort_t)(r >> 16);
}
__device__ inline float2 up2(uint_t w) { return make_float2(bf2f((ushort_t)(w & 0xFFFFu)), bf2f((ushort_t)(w >> 16))); }
// dtype-flexible loads (bf=1: buffer holds bf16; bf=0: fp32)
__device__ inline float ld_f(const void* p, size_t i, int bf) { return bf ? bf2f(((const ushort_t*)p)[i]) : ((const float*)p)[i]; }
__device__ inline ushort_t ld_b(const void* p, size_t i, int bf) { return bf ? ((const ushort_t*)p)[i] : f2bf(((const float*)p)[i]); }
// edge fetch with int64/int32 handling; self-loops appended at e >= E_in
__device__ inline void edge_sd(const int* __restrict__ ei, int e, int E_in, int i64, int& src, int& dst) {
    if (e < E_in) {
        if (i64) { src = ei[2 * (size_t)e]; dst = ei[2 * ((size_t)E_in + e)]; }
        else     { src = ei[e];             dst = ei[(size_t)E_in + e]; }
    } else { src = dst = e - E_in; }
}

// ---------------- dtype detection ----------------
// flags[0]=1 if float buffers are bf16-packed; flags[1]=1 if edge_index is int64
__global__ void k_detect(const uint_t* __restrict__ xw, const int* __restrict__ ei, int* flags) {
    __shared__ int cnt;
    if (threadIdx.x == 0) cnt = 0;
    __syncthreads();
    uint_t w = xw[threadIdx.x];           // 256 words of x
    int eb = (int)((w >> 7) & 0xFFu);     // low-half bf16 exponent field
    if (eb >= 113 && eb <= 142) atomicAdd(&cnt, 1);
    __syncthreads();
    if (threadIdx.x == 0) {
        flags[0] = (cnt > 128) ? 1 : 0;
        int z = 0;
        #pragma unroll
        for (int i = 1; i < 16; i += 2) z += (ei[i] == 0) ? 1 : 0;  // int64 high words
        flags[1] = (z == 8) ? 1 : 0;
    }
}

// ---------------- input normalization ----------------
__global__ void k_cvt_x(const void* __restrict__ x, ushort_t* __restrict__ xb, int n, const int* flags) {
    int i = blockIdx.x * blockDim.x + threadIdx.x;
    if (i < n) xb[i] = ld_b(x, i, flags[0]);
}

__global__ void k_cvt_params(const void* Wl1, const void* Wr1, const void* att1, const void* b1,
                             const void* Wl2, const void* Wr2, const void* att2, const void* b2,
                             const void* Wo, const void* bo,
                             ushort_t* Wl1b, ushort_t* Wr1b, ushort_t* Wl2b, ushort_t* Wr2b,
                             float* att1f, float* b1f, float* att2f, float* b2f, float* Wof, float* bof,
                             int sW1, int sW2, int satt1, int sb1, int satt2, int sb2, int sWo, int sbo,
                             const int* flags) {
    int i = blockIdx.x * blockDim.x + threadIdx.x;
    int bf = flags[0];
    if (i < sW1) { Wl1b[i] = ld_b(Wl1, i, bf); Wr1b[i] = ld_b(Wr1, i, bf); }
    if (i < sW2) { Wl2b[i] = ld_b(Wl2, i, bf); Wr2b[i] = ld_b(Wr2, i, bf); }
    if (i < satt1) att1f[i] = ld_f(att1, i, bf);
    if (i < sb1)   b1f[i]   = ld_f(b1, i, bf);
    if (i < satt2) att2f[i] = ld_f(att2, i, bf);
    if (i < sb2)   b2f[i]   = ld_f(b2, i, bf);
    if (i < sWo)   Wof[i]   = ld_f(Wo, i, bf);
    if (i < sbo)   bof[i]   = ld_f(bo, i, bf);
}

// ---------------- init: zero degrees ----------------
__global__ void k_init(int* deg, int n) {
    int i = blockIdx.x * blockDim.x + threadIdx.x;
    if (i < n) deg[i] = 0;
}

// ---------------- CSR build over dst ----------------
__global__ void k_count(const int* __restrict__ ei, int E_in, int Etot, const int* flags, int* deg) {
    int e = blockIdx.x * blockDim.x + threadIdx.x;
    if (e >= Etot) return;
    int src, dst; edge_sd(ei, e, E_in, flags[1], src, dst);
    atomicAdd(&deg[dst], 1);
}

__global__ void k_scan(const int* __restrict__ deg, int* offs, int* cursor, int n) {
    __shared__ int sh[1024];
    int t = threadIdx.x;
    int chunk = (n + 1023) / 1024;
    int s = t * chunk, e = min(s + chunk, n);
    int local = 0;
    for (int i = s; i < e; i++) local += deg[i];
    sh[t] = local; __syncthreads();
    for (int off = 1; off < 1024; off <<= 1) {
        int v = (t >= off) ? sh[t - off] : 0;
        __syncthreads();
        sh[t] += v; __syncthreads();
    }
    int run = sh[t] - local;   // exclusive base
    for (int i = s; i < e; i++) { offs[i] = run; cursor[i] = run; run += deg[i]; }
    if (e == n) offs[n] = run;
}

__global__ void k_fill(const int* __restrict__ ei, int E_in, int Etot, const int* flags,
                       int* cursor, int* s_src) {
    int e = blockIdx.x * blockDim.x + threadIdx.x;
    if (e >= Etot) return;
    int src, dst; edge_sd(ei, e, E_in, flags[1], src, dst);
    int p = atomicAdd(&cursor[dst], 1);
    s_src[p] = src;
}

// ------- MFMA GEMM: Y[M,NOUT](bf16) = X[M,128](bf16) @ W[128,NOUT](bf16) -------
template <int NOUT>
__global__ __launch_bounds__(256) void k_gemm(const ushort_t* __restrict__ X,
                                              const ushort_t* __restrict__ W,
                                              ushort_t* __restrict__ Y, int M) {
    const int lane = threadIdx.x & 63, wid = threadIdx.x >> 6;
    const int ntiles = M >> 4;
    int rt = blockIdx.x * 4 + wid;
    if (rt >= ntiles) return;
    const int colbase = blockIdx.y * 64;
    const int quad = lane >> 4, lo = lane & 15;

    bf16x8 bfr[4][4];  // B[k=quad*8+j][n=colbase+nt*16+lo]
    #pragma unroll
    for (int nt = 0; nt < 4; nt++) {
        int n = colbase + nt * 16 + lo;
        #pragma unroll
        for (int kc = 0; kc < 4; kc++) {
            int kb = kc * 32 + quad * 8;
            bf16x8 b;
            #pragma unroll
            for (int j = 0; j < 8; j++) b[j] = (short)W[(size_t)(kb + j) * NOUT + n];
            bfr[nt][kc] = b;
        }
    }

    f32x4 acc[4];
    #pragma unroll
    for (int nt = 0; nt < 4; nt++) acc[nt] = (f32x4){0.f, 0.f, 0.f, 0.f};

    int r = rt * 16 + lo;
    const ushort_t* xrow = X + (size_t)r * 128 + quad * 8;
    #pragma unroll
    for (int kc = 0; kc < 4; kc++) {
        bf16x8 a = *(const bf16x8*)(xrow + kc * 32);   // 16B aligned
        #pragma unroll
        for (int nt = 0; nt < 4; nt++)
            acc[nt] = __builtin_amdgcn_mfma_f32_16x16x32_bf16(a, bfr[nt][kc], acc[nt], 0, 0, 0);
    }
    // C/D: col = lane&15, row = quad*4 + reg  [m89-verified]
    #pragma unroll
    for (int nt = 0; nt < 4; nt++) {
        int col = colbase + nt * 16 + lo;
        #pragma unroll
        for (int ri = 0; ri < 4; ri++) {
            int row = rt * 16 + quad * 4 + ri;
            Y[(size_t)row * NOUT + col] = f2bf(acc[nt][ri]);
        }
    }
}

// ======== layer 1 FUSED: online-softmax gather + bias + relu -> h1 (bf16) ========
// wave per node; lane covers channels {2l, 2l+1}; head = l>>4 (16 lanes per head).
__global__ __launch_bounds__(256) void k_l1(const ushort_t* __restrict__ xl,
                                            const ushort_t* __restrict__ xr,
                                            const int* __restrict__ offs,
                                            const int* __restrict__ s_src,
                                            const float* __restrict__ att,
                                            const float* __restrict__ b1,
                                            int n, ushort_t* __restrict__ h1) {
    int lane = threadIdx.x & 63, wid = threadIdx.x >> 6;
    int node = blockIdx.x * 4 + wid;
    if (node >= n) return;
    float2 xv = up2(*(const uint_t*)(xr + (size_t)node * 128 + 2 * lane));  // xr[dst] resident
    float at0 = att[2 * lane], at1 = att[2 * lane + 1];
    int o0 = offs[node], o1 = offs[node + 1];

    float m = -__builtin_inff(), s = 0.f, a0 = 0.f, a1 = 0.f;
    uint_t w = *(const uint_t*)(xl + (size_t)s_src[o0] * 128 + 2 * lane);   // prefetch first
    for (int i = o0; i < o1; i++) {
        uint_t wc = w;
        if (i + 1 < o1)
            w = *(const uint_t*)(xl + (size_t)s_src[i + 1] * 128 + 2 * lane);  // prefetch next
        float2 v = up2(wc);
        float m0 = v.x + xv.x, m1 = v.y + xv.y;
        m0 = m0 > 0.f ? m0 : NEG_SLOPE * m0;
        m1 = m1 > 0.f ? m1 : NEG_SLOPE * m1;
        float e = m0 * at0 + m1 * at1;
        #pragma unroll
        for (int o = 1; o < 16; o <<= 1) e += __shfl_xor(e, o, 64);  // within 16-lane head group
        float mn = fmaxf(m, e);
        float corr = __expf(m - mn);     // first iter: exp(-inf)=0
        float p = __expf(e - mn);
        s = s * corr + p;
        a0 = a0 * corr + p * v.x;
        a1 = a1 * corr + p * v.y;
        m = mn;
    }
    float inv = 1.f / s;
    float r0 = fmaxf(a0 * inv + b1[2 * lane],     0.f);
    float r1 = fmaxf(a1 * inv + b1[2 * lane + 1], 0.f);
    uint_t pack = (uint_t)f2bf(r0) | ((uint_t)f2bf(r1) << 16);
    *(uint_t*)(h1 + (size_t)node * 128 + 2 * lane) = pack;
}

// ======== layer 2 FUSED: online-softmax gather + mean-heads + b2 + decoder ========
// block per node; wave = head; lane covers channels {2l, 2l+1} of its head's 128.
__global__ __launch_bounds__(256) void k_l2(const ushort_t* __restrict__ xl,
                                            const ushort_t* __restrict__ xr,
                                            const int* __restrict__ offs,
                                            const int* __restrict__ s_src,
                                            const float* __restrict__ att,
                                            const float* __restrict__ b2,
                                            const float* __restrict__ Wo,
                                            const float* __restrict__ bo,
                                            int n, const int* flags, void* dout) {
    __shared__ float part[4][128];
    __shared__ float hbuf[128];
    int node = blockIdx.x;
    int h = threadIdx.x >> 6, lane = threadIdx.x & 63;
    size_t choff = (size_t)h * 128 + 2 * lane;
    float2 xv = up2(*(const uint_t*)(xr + (size_t)node * 512 + choff));     // xr[dst] resident
    float at0 = att[h * 128 + 2 * lane], at1 = att[h * 128 + 2 * lane + 1];
    int o0 = offs[node], o1 = offs[node + 1];

    float m = -__builtin_inff(), s = 0.f, a0 = 0.f, a1 = 0.f;
    uint_t w = *(const uint_t*)(xl + (size_t)s_src[o0] * 512 + choff);      // prefetch first
    for (int i = o0; i < o1; i++) {
        uint_t wc = w;
        if (i + 1 < o1)
            w = *(const uint_t*)(xl + (size_t)s_src[i + 1] * 512 + choff);  // prefetch next
        float2 v = up2(wc);
        float m0 = v.x + xv.x, m1 = v.y + xv.y;
        m0 = m0 > 0.f ? m0 : NEG_SLOPE * m0;
        m1 = m1 > 0.f ? m1 : NEG_SLOPE * m1;
        float e = m0 * at0 + m1 * at1;
        #pragma unroll
        for (int o = 1; o < 64; o <<= 1) e += __shfl_xor(e, o, 64);  // full-wave dot
        float mn = fmaxf(m, e);
        float corr = __expf(m - mn);
        float p = __expf(e - mn);
        s = s * corr + p;
        a0 = a0 * corr + p * v.x;
        a1 = a1 * corr + p * v.y;
        m = mn;
    }
    float inv = 1.f / s;
    part[h][2 * lane]     = a0 * inv;
    part[h][2 * lane + 1] = a1 * inv;
    __syncthreads();
    int t = threadIdx.x;
    int bf = flags[0];
    if (t < 128) {
        float hm = 0.25f * (part[0][t] + part[1][t] + part[2][t] + part[3][t]) + b2[t];
        hbuf[t] = hm;
        size_t oidx = (size_t)n * 2 + (size_t)node * 128 + t;
        if (bf) ((ushort_t*)dout)[oidx] = f2bf(hm);
        else    ((float*)dout)[oidx]    = hm;
    }
    __syncthreads();
    if (h < 2) {  // decoder: out[node,h] = dot(hbuf, Wo[:,h]) + bo[h]
        float v = hbuf[lane] * Wo[lane * 2 + h] + hbuf[lane + 64] * Wo[(lane + 64) * 2 + h];
        #pragma unroll
        for (int o = 32; o > 0; o >>= 1) v += __shfl_xor(v, o, 64);
        if (lane == 0) {
            float r = v + bo[h];
            size_t oidx = (size_t)node * 2 + h;
            if (bf) ((ushort_t*)dout)[oidx] = f2bf(r);
            else    ((float*)dout)[oidx]    = r;
        }
    }
}

extern "C" void kernel_launch(void* const* d_in, const int* in_sizes, int n_in,
                              void* d_out, int out_size, void* d_ws, size_t ws_size,
                              hipStream_t stream) {
    const void* x    = d_in[0];
    const int*  ei   = (const int*)d_in[1];
    const void* Wl1  = d_in[2];
    const void* Wr1  = d_in[3];
    const void* att1 = d_in[4];
    const void* b1   = d_in[5];
    const void* Wl2  = d_in[6];
    const void* Wr2  = d_in[7];
    const void* att2 = d_in[8];
    const void* b2   = d_in[9];
    const void* Wo   = d_in[10];
    const void* bo   = d_in[11];

    const int N    = in_sizes[0] / 128;   // 50000
    const int E_in = in_sizes[1] / 2;     // 800000
    const int Etot = E_in + N;

    const int sW1 = in_sizes[2], sW2 = in_sizes[6];
    const int satt1 = in_sizes[4], sb1 = in_sizes[5];
    const int satt2 = in_sizes[8], sb2 = in_sizes[9];
    const int sWo = in_sizes[10], sbo = in_sizes[11];

    char* w = (char*)d_ws;
    size_t off = 0;
    auto take = [&](size_t bytes) -> void* {
        void* p = w + off;
        off += (bytes + 255) & ~(size_t)255;
        return p;
    };
    int*      flags  = (int*)take(256);
    ushort_t* xb     = (ushort_t*)take((size_t)N * 128 * sizeof(ushort_t));
    ushort_t* Wl1b   = (ushort_t*)take((size_t)sW1 * 2);
    ushort_t* Wr1b   = (ushort_t*)take((size_t)sW1 * 2);
    ushort_t* Wl2b   = (ushort_t*)take((size_t)sW2 * 2);
    ushort_t* Wr2b   = (ushort_t*)take((size_t)sW2 * 2);
    float*    att1f  = (float*)take((size_t)satt1 * 4);
    float*    b1f    = (float*)take((size_t)sb1 * 4);
    float*    att2f  = (float*)take((size_t)satt2 * 4);
    float*    b2f    = (float*)take((size_t)sb2 * 4);
    float*    Wof    = (float*)take((size_t)sWo * 4);
    float*    bof    = (float*)take((size_t)sbo * 4);
    int*      deg    = (int*)take((size_t)N * sizeof(int));
    int*      offs   = (int*)take((size_t)(N + 1) * sizeof(int));
    int*      cursor = (int*)take((size_t)(N + 1) * sizeof(int));
    int*      s_src  = (int*)take((size_t)Etot * sizeof(int));
    ushort_t* h1     = (ushort_t*)take((size_t)N * 128 * sizeof(ushort_t));
    ushort_t* xl1b   = (ushort_t*)take((size_t)N * 128 * sizeof(ushort_t));
    ushort_t* xr1b   = (ushort_t*)take((size_t)N * 128 * sizeof(ushort_t));
    ushort_t* xl2b   = (ushort_t*)take((size_t)N * 512 * sizeof(ushort_t));
    ushort_t* xr2b   = (ushort_t*)take((size_t)N * 512 * sizeof(ushort_t));

    dim3 b256(256);
    k_detect<<<1, b256, 0, stream>>>((const uint_t*)x, ei, flags);
    k_cvt_x<<<(N * 128 + 255) / 256, b256, 0, stream>>>(x, xb, N * 128, flags);
    k_cvt_params<<<(sW2 + 255) / 256, b256, 0, stream>>>(
        Wl1, Wr1, att1, b1, Wl2, Wr2, att2, b2, Wo, bo,
        Wl1b, Wr1b, Wl2b, Wr2b, att1f, b1f, att2f, b2f, Wof, bof,
        sW1, sW2, satt1, sb1, satt2, sb2, sWo, sbo, flags);

    k_init<<<(N + 255) / 256, b256, 0, stream>>>(deg, N);
    k_count<<<(Etot + 255) / 256, b256, 0, stream>>>(ei, E_in, Etot, flags, deg);
    k_scan<<<1, 1024, 0, stream>>>(deg, offs, cursor, N);
    k_fill<<<(Etot + 255) / 256, b256, 0, stream>>>(ei, E_in, Etot, flags, cursor, s_src);

    dim3 g1((N / 16 + 3) / 4, 128 / 64);
    k_gemm<128><<<g1, b256, 0, stream>>>(xb, Wl1b, xl1b, N);
    k_gemm<128><<<g1, b256, 0, stream>>>(xb, Wr1b, xr1b, N);
    k_l1<<<(N + 3) / 4, b256, 0, stream>>>(xl1b, xr1b, offs, s_src, att1f, b1f, N, h1);

    dim3 g2((N / 16 + 3) / 4, 512 / 64);
    k_gemm<512><<<g2, b256, 0, stream>>>(h1, Wl2b, xl2b, N);
    k_gemm<512><<<g2, b256, 0, stream>>>(h1, Wr2b, xr2b, N);

    k_l2<<<N, b256, 0, stream>>>(xl2b, xr2b, offs, s_src, att2f, b2f, Wof, bof, N, flags, d_out);
}

// Round 4
// 693.894 us; speedup vs baseline: 1.7972x; 1.2151x over previous
//
#include <hip/hip_runtime.h>

#define NEG_SLOPE 0.2f
#define NEG_INF (-__builtin_inff())

typedef unsigned short ushort_t;
typedef unsigned int uint_t;
typedef __attribute__((ext_vector_type(8))) short bf16x8;   // 8 bf16 in 4 VGPRs
typedef __attribute__((ext_vector_type(4))) float f32x4;

__device__ inline float bf2f(ushort_t u) { union { uint_t i; float f; } v; v.i = ((uint_t)u) << 16; return v.f; }
__device__ inline ushort_t f2bf(float f) {
    union { float f; uint_t u; } v; v.f = f;
    uint_t r = v.u + 0x7fffu + ((v.u >> 16) & 1u);
    return (ushort_t)(r >> 16);
}
__device__ inline float2 up2(uint_t w) { return make_float2(bf2f((ushort_t)(w & 0xFFFFu)), bf2f((ushort_t)(w >> 16))); }
// packed-pair helpers (compiler may map to v_pk_* on gfx950)
__device__ inline float2 pk_add(float2 a, float2 b) { return make_float2(a.x + b.x, a.y + b.y); }
__device__ inline float2 pk_fma(float2 a, float2 b, float2 c) { return make_float2(fmaf(a.x, b.x, c.x), fmaf(a.y, b.y, c.y)); }
__device__ inline float2 pk_leaky(float2 m) {
    return make_float2(fmaxf(m.x, 0.f) + NEG_SLOPE * fminf(m.x, 0.f),
                       fmaxf(m.y, 0.f) + NEG_SLOPE * fminf(m.y, 0.f));
}
__device__ inline float2 pk_comb(float2 a, float c1, float2 b, float c2) {  // a*c1 + b*c2
    return make_float2(fmaf(a.x, c1, b.x * c2), fmaf(a.y, c1, b.y * c2));
}
// dtype-flexible loads (bf=1: buffer holds bf16; bf=0: fp32)
__device__ inline float ld_f(const void* p, size_t i, int bf) { return bf ? bf2f(((const ushort_t*)p)[i]) : ((const float*)p)[i]; }
__device__ inline ushort_t ld_b(const void* p, size_t i, int bf) { return bf ? ((const ushort_t*)p)[i] : f2bf(((const float*)p)[i]); }
// edge fetch with int64/int32 handling; self-loops appended at e >= E_in
__device__ inline void edge_sd(const int* __restrict__ ei, int e, int E_in, int i64, int& src, int& dst) {
    if (e < E_in) {
        if (i64) { src = ei[2 * (size_t)e]; dst = ei[2 * ((size_t)E_in + e)]; }
        else     { src = ei[e];             dst = ei[(size_t)E_in + e]; }
    } else { src = dst = e - E_in; }
}

// ---------------- dtype detection ----------------
__global__ void k_detect(const uint_t* __restrict__ xw, const int* __restrict__ ei, int* flags) {
    __shared__ int cnt;
    if (threadIdx.x == 0) cnt = 0;
    __syncthreads();
    uint_t w = xw[threadIdx.x];
    int eb = (int)((w >> 7) & 0xFFu);
    if (eb >= 113 && eb <= 142) atomicAdd(&cnt, 1);
    __syncthreads();
    if (threadIdx.x == 0) {
        flags[0] = (cnt > 128) ? 1 : 0;
        int z = 0;
        #pragma unroll
        for (int i = 1; i < 16; i += 2) z += (ei[i] == 0) ? 1 : 0;
        flags[1] = (z == 8) ? 1 : 0;
    }
}

// ---------------- input normalization ----------------
__global__ void k_cvt_x(const void* __restrict__ x, ushort_t* __restrict__ xb, int n, const int* flags) {
    int i = blockIdx.x * blockDim.x + threadIdx.x;
    if (i < n) xb[i] = ld_b(x, i, flags[0]);
}

__global__ void k_cvt_params(const void* Wl1, const void* Wr1, const void* att1, const void* b1,
                             const void* Wl2, const void* Wr2, const void* att2, const void* b2,
                             const void* Wo, const void* bo,
                             ushort_t* Wl1b, ushort_t* Wr1b, ushort_t* Wl2b, ushort_t* Wr2b,
                             float* att1f, float* b1f, float* att2f, float* b2f, float* Wof, float* bof,
                             int sW1, int sW2, int satt1, int sb1, int satt2, int sb2, int sWo, int sbo,
                             const int* flags) {
    int i = blockIdx.x * blockDim.x + threadIdx.x;
    int bf = flags[0];
    if (i < sW1) { Wl1b[i] = ld_b(Wl1, i, bf); Wr1b[i] = ld_b(Wr1, i, bf); }
    if (i < sW2) { Wl2b[i] = ld_b(Wl2, i, bf); Wr2b[i] = ld_b(Wr2, i, bf); }
    if (i < satt1) att1f[i] = ld_f(att1, i, bf);
    if (i < sb1)   b1f[i]   = ld_f(b1, i, bf);
    if (i < satt2) att2f[i] = ld_f(att2, i, bf);
    if (i < sb2)   b2f[i]   = ld_f(b2, i, bf);
    if (i < sWo)   Wof[i]   = ld_f(Wo, i, bf);
    if (i < sbo)   bof[i]   = ld_f(bo, i, bf);
}

// transpose bf16 W[K][NOUT] -> WT[NOUT][K] for contiguous B-frag loads
__global__ void k_transpose2(const ushort_t* __restrict__ Wa, const ushort_t* __restrict__ Wb,
                             ushort_t* __restrict__ WTa, ushort_t* __restrict__ WTb,
                             int K, int NOUT) {
    int i = blockIdx.x * blockDim.x + threadIdx.x;
    if (i >= K * NOUT) return;
    int n = i >> 7, k = i & 127;          // K == 128 always here
    WTa[i] = Wa[(size_t)k * NOUT + n];
    WTb[i] = Wb[(size_t)k * NOUT + n];
}

// ---------------- init + CSR build over dst ----------------
__global__ void k_init(int* deg, int n) {
    int i = blockIdx.x * blockDim.x + threadIdx.x;
    if (i < n) deg[i] = 0;
}

__global__ void k_count(const int* __restrict__ ei, int E_in, int Etot, const int* flags, int* deg) {
    int e = blockIdx.x * blockDim.x + threadIdx.x;
    if (e >= Etot) return;
    int src, dst; edge_sd(ei, e, E_in, flags[1], src, dst);
    atomicAdd(&deg[dst], 1);
}

__global__ void k_scan(const int* __restrict__ deg, int* offs, int* cursor, int n) {
    __shared__ int sh[1024];
    int t = threadIdx.x;
    int chunk = (n + 1023) / 1024;
    int s = t * chunk, e = min(s + chunk, n);
    int local = 0;
    for (int i = s; i < e; i++) local += deg[i];
    sh[t] = local; __syncthreads();
    for (int off = 1; off < 1024; off <<= 1) {
        int v = (t >= off) ? sh[t - off] : 0;
        __syncthreads();
        sh[t] += v; __syncthreads();
    }
    int run = sh[t] - local;
    for (int i = s; i < e; i++) { offs[i] = run; cursor[i] = run; run += deg[i]; }
    if (e == n) offs[n] = run;
}

__global__ void k_fill(const int* __restrict__ ei, int E_in, int Etot, const int* flags,
                       int* cursor, int* s_src) {
    int e = blockIdx.x * blockDim.x + threadIdx.x;
    if (e >= Etot) return;
    int src, dst; edge_sd(ei, e, E_in, flags[1], src, dst);
    int p = atomicAdd(&cursor[dst], 1);
    s_src[p] = src;
}

// ------- MFMA GEMM: Y[M,NOUT](bf16) = X[M,128](bf16) @ W, B from WT[NOUT][128] -------
template <int NOUT>
__global__ __launch_bounds__(256) void k_gemm(const ushort_t* __restrict__ X,
                                              const ushort_t* __restrict__ WT,
                                              ushort_t* __restrict__ Y, int M) {
    const int lane = threadIdx.x & 63, wid = threadIdx.x >> 6;
    const int ntiles = M >> 4;
    int rt = blockIdx.x * 4 + wid;
    if (rt >= ntiles) return;
    const int colbase = blockIdx.y * 64;
    const int quad = lane >> 4, lo = lane & 15;

    bf16x8 bfr[4][4];  // B[k=quad*8+j][n=colbase+nt*16+lo] from WT: contiguous 16B
    #pragma unroll
    for (int nt = 0; nt < 4; nt++) {
        const ushort_t* wrow = WT + (size_t)(colbase + nt * 16 + lo) * 128 + quad * 8;
        #pragma unroll
        for (int kc = 0; kc < 4; kc++)
            bfr[nt][kc] = *(const bf16x8*)(wrow + kc * 32);
    }

    f32x4 acc[4];
    #pragma unroll
    for (int nt = 0; nt < 4; nt++) acc[nt] = (f32x4){0.f, 0.f, 0.f, 0.f};

    int r = rt * 16 + lo;
    const ushort_t* xrow = X + (size_t)r * 128 + quad * 8;
    #pragma unroll
    for (int kc = 0; kc < 4; kc++) {
        bf16x8 a = *(const bf16x8*)(xrow + kc * 32);
        #pragma unroll
        for (int nt = 0; nt < 4; nt++)
            acc[nt] = __builtin_amdgcn_mfma_f32_16x16x32_bf16(a, bfr[nt][kc], acc[nt], 0, 0, 0);
    }
    // C/D: col = lane&15, row = quad*4 + reg  [m89-verified]
    #pragma unroll
    for (int nt = 0; nt < 4; nt++) {
        int col = colbase + nt * 16 + lo;
        #pragma unroll
        for (int ri = 0; ri < 4; ri++) {
            int row = rt * 16 + quad * 4 + ri;
            Y[(size_t)row * NOUT + col] = f2bf(acc[nt][ri]);
        }
    }
}

// ======== layer 1 FUSED: slot-parallel online-softmax gather -> h1 (bf16) ========
// wave per node. 4 slots x 16 lanes; lane covers 8 ch (full 128-ch row per slot).
// head = (lane&15)>>2 (4 lanes/head); per-slot independent online softmax, merged at end.
__global__ __launch_bounds__(256) void k_l1(const ushort_t* __restrict__ xl,
                                            const ushort_t* __restrict__ xr,
                                            const int* __restrict__ offs,
                                            const int* __restrict__ s_src,
                                            const float* __restrict__ att,
                                            const float* __restrict__ b1,
                                            int n, ushort_t* __restrict__ h1) {
    int lane = threadIdx.x & 63, wid = threadIdx.x >> 6;
    int node = blockIdx.x * 4 + wid;
    if (node >= n) return;
    int slot = lane >> 4, sub = lane & 15;
    int chb = sub * 8;

    uint4 xw = *(const uint4*)(xr + (size_t)node * 128 + chb);
    float2 xv[4] = {up2(xw.x), up2(xw.y), up2(xw.z), up2(xw.w)};
    float2 at[4];
    #pragma unroll
    for (int j = 0; j < 4; j++) at[j] = make_float2(att[chb + 2 * j], att[chb + 2 * j + 1]);

    int o0 = offs[node], o1 = offs[node + 1];
    float m = NEG_INF, s = 0.f;
    float2 acc[4] = {{0.f,0.f},{0.f,0.f},{0.f,0.f},{0.f,0.f}};

    int i = o0 + slot;
    uint4 w;
    if (i < o1) w = *(const uint4*)(xl + (size_t)s_src[i] * 128 + chb);
    while (i < o1) {
        uint4 wc = w;
        int in = i + 4;
        if (in < o1) w = *(const uint4*)(xl + (size_t)s_src[in] * 128 + chb);
        float2 v[4] = {up2(wc.x), up2(wc.y), up2(wc.z), up2(wc.w)};
        float2 ep = make_float2(0.f, 0.f);
        #pragma unroll
        for (int j = 0; j < 4; j++)
            ep = pk_fma(pk_leaky(pk_add(v[j], xv[j])), at[j], ep);
        float e = ep.x + ep.y;
        e += __shfl_xor(e, 1, 64);
        e += __shfl_xor(e, 2, 64);          // reduce over 4-lane head group
        float mn = fmaxf(m, e);
        float corr = (m > NEG_INF) ? __expf(m - mn) : 0.f;
        float p = __expf(e - mn);
        s = fmaf(s, corr, p);
        #pragma unroll
        for (int j = 0; j < 4; j++) acc[j] = pk_comb(acc[j], corr, v[j], p);
        m = mn;
        i = in;
    }
    // merge the 4 slots (butterfly xor 16, 32) with softmax rescale
    #pragma unroll
    for (int off = 16; off <= 32; off <<= 1) {
        float mo = __shfl_xor(m, off, 64);
        float so = __shfl_xor(s, off, 64);
        float2 ao[4];
        #pragma unroll
        for (int j = 0; j < 4; j++) {
            ao[j].x = __shfl_xor(acc[j].x, off, 64);
            ao[j].y = __shfl_xor(acc[j].y, off, 64);
        }
        float mn = fmaxf(m, mo);
        float c1 = (m  > NEG_INF) ? __expf(m  - mn) : 0.f;
        float c2 = (mo > NEG_INF) ? __expf(mo - mn) : 0.f;
        s = s * c1 + so * c2;
        #pragma unroll
        for (int j = 0; j < 4; j++) acc[j] = pk_comb(acc[j], c1, ao[j], c2);
        m = mn;
    }
    if (slot == 0) {
        float inv = 1.f / s;
        uint_t pk[4];
        #pragma unroll
        for (int j = 0; j < 4; j++) {
            float r0 = fmaxf(fmaf(acc[j].x, inv, b1[chb + 2 * j]),     0.f);
            float r1 = fmaxf(fmaf(acc[j].y, inv, b1[chb + 2 * j + 1]), 0.f);
            pk[j] = (uint_t)f2bf(r0) | ((uint_t)f2bf(r1) << 16);
        }
        *(uint4*)(h1 + (size_t)node * 128 + chb) = make_uint4(pk[0], pk[1], pk[2], pk[3]);
    }
}

// ======== layer 2 FUSED: slot-parallel online softmax + mean-heads + b2 + decoder ========
// block per node; wave = head. 4 slots x 16 lanes x 8 ch (head's 128 ch per slot).
__global__ __launch_bounds__(256) void k_l2(const ushort_t* __restrict__ xl,
                                            const ushort_t* __restrict__ xr,
                                            const int* __restrict__ offs,
                                            const int* __restrict__ s_src,
                                            const float* __restrict__ att,
                                            const float* __restrict__ b2,
                                            const float* __restrict__ Wo,
                                            const float* __restrict__ bo,
                                            int n, const int* flags, void* dout) {
    __shared__ float part[4][128];
    __shared__ float hbuf[128];
    int node = blockIdx.x;
    int h = threadIdx.x >> 6, lane = threadIdx.x & 63;
    int slot = lane >> 4, sub = lane & 15;
    int chb = sub * 8;
    size_t choff = (size_t)h * 128 + chb;

    uint4 xw = *(const uint4*)(xr + (size_t)node * 512 + choff);
    float2 xv[4] = {up2(xw.x), up2(xw.y), up2(xw.z), up2(xw.w)};
    float2 at[4];
    #pragma unroll
    for (int j = 0; j < 4; j++) at[j] = make_float2(att[choff + 2 * j], att[choff + 2 * j + 1]);

    int o0 = offs[node], o1 = offs[node + 1];
    float m = NEG_INF, s = 0.f;
    float2 acc[4] = {{0.f,0.f},{0.f,0.f},{0.f,0.f},{0.f,0.f}};

    int i = o0 + slot;
    uint4 w;
    if (i < o1) w = *(const uint4*)(xl + (size_t)s_src[i] * 512 + choff);
    while (i < o1) {
        uint4 wc = w;
        int in = i + 4;
        if (in < o1) w = *(const uint4*)(xl + (size_t)s_src[in] * 512 + choff);
        float2 v[4] = {up2(wc.x), up2(wc.y), up2(wc.z), up2(wc.w)};
        float2 ep = make_float2(0.f, 0.f);
        #pragma unroll
        for (int j = 0; j < 4; j++)
            ep = pk_fma(pk_leaky(pk_add(v[j], xv[j])), at[j], ep);
        float e = ep.x + ep.y;
        #pragma unroll
        for (int o = 1; o < 16; o <<= 1) e += __shfl_xor(e, o, 64);  // 16-lane slot reduce
        float mn = fmaxf(m, e);
        float corr = (m > NEG_INF) ? __expf(m - mn) : 0.f;
        float p = __expf(e - mn);
        s = fmaf(s, corr, p);
        #pragma unroll
        for (int j = 0; j < 4; j++) acc[j] = pk_comb(acc[j], corr, v[j], p);
        m = mn;
        i = in;
    }
    // merge slots
    #pragma unroll
    for (int off = 16; off <= 32; off <<= 1) {
        float mo = __shfl_xor(m, off, 64);
        float so = __shfl_xor(s, off, 64);
        float2 ao[4];
        #pragma unroll
        for (int j = 0; j < 4; j++) {
            ao[j].x = __shfl_xor(acc[j].x, off, 64);
            ao[j].y = __shfl_xor(acc[j].y, off, 64);
        }
        float mn = fmaxf(m, mo);
        float c1 = (m  > NEG_INF) ? __expf(m  - mn) : 0.f;
        float c2 = (mo > NEG_INF) ? __expf(mo - mn) : 0.f;
        s = s * c1 + so * c2;
        #pragma unroll
        for (int j = 0; j < 4; j++) acc[j] = pk_comb(acc[j], c1, ao[j], c2);
        m = mn;
    }
    if (slot == 0) {
        float inv = 1.f / s;
        #pragma unroll
        for (int j = 0; j < 4; j++) {
            part[h][chb + 2 * j]     = acc[j].x * inv;
            part[h][chb + 2 * j + 1] = acc[j].y * inv;
        }
    }
    __syncthreads();
    int t = threadIdx.x;
    int bf = flags[0];
    if (t < 128) {
        float hm = 0.25f * (part[0][t] + part[1][t] + part[2][t] + part[3][t]) + b2[t];
        hbuf[t] = hm;
        size_t oidx = (size_t)n * 2 + (size_t)node * 128 + t;
        if (bf) ((ushort_t*)dout)[oidx] = f2bf(hm);
        else    ((float*)dout)[oidx]    = hm;
    }
    __syncthreads();
    if (h < 2) {  // decoder
        float v = hbuf[lane] * Wo[lane * 2 + h] + hbuf[lane + 64] * Wo[(lane + 64) * 2 + h];
        #pragma unroll
        for (int o = 32; o > 0; o >>= 1) v += __shfl_xor(v, o, 64);
        if (lane == 0) {
            float r = v + bo[h];
            size_t oidx = (size_t)node * 2 + h;
            if (bf) ((ushort_t*)dout)[oidx] = f2bf(r);
            else    ((float*)dout)[oidx]    = r;
        }
    }
}

extern "C" void kernel_launch(void* const* d_in, const int* in_sizes, int n_in,
                              void* d_out, int out_size, void* d_ws, size_t ws_size,
                              hipStream_t stream) {
    const void* x    = d_in[0];
    const int*  ei   = (const int*)d_in[1];
    const void* Wl1  = d_in[2];
    const void* Wr1  = d_in[3];
    const void* att1 = d_in[4];
    const void* b1   = d_in[5];
    const void* Wl2  = d_in[6];
    const void* Wr2  = d_in[7];
    const void* att2 = d_in[8];
    const void* b2   = d_in[9];
    const void* Wo   = d_in[10];
    const void* bo   = d_in[11];

    const int N    = in_sizes[0] / 128;   // 50000
    const int E_in = in_sizes[1] / 2;     // 800000
    const int Etot = E_in + N;

    const int sW1 = in_sizes[2], sW2 = in_sizes[6];
    const int satt1 = in_sizes[4], sb1 = in_sizes[5];
    const int satt2 = in_sizes[8], sb2 = in_sizes[9];
    const int sWo = in_sizes[10], sbo = in_sizes[11];

    char* w = (char*)d_ws;
    size_t off = 0;
    auto take = [&](size_t bytes) -> void* {
        void* p = w + off;
        off += (bytes + 255) & ~(size_t)255;
        return p;
    };
    int*      flags  = (int*)take(256);
    ushort_t* xb     = (ushort_t*)take((size_t)N * 128 * sizeof(ushort_t));
    ushort_t* Wl1b   = (ushort_t*)take((size_t)sW1 * 2);
    ushort_t* Wr1b   = (ushort_t*)take((size_t)sW1 * 2);
    ushort_t* Wl2b   = (ushort_t*)take((size_t)sW2 * 2);
    ushort_t* Wr2b   = (ushort_t*)take((size_t)sW2 * 2);
    ushort_t* WTl1   = (ushort_t*)take((size_t)sW1 * 2);
    ushort_t* WTr1   = (ushort_t*)take((size_t)sW1 * 2);
    ushort_t* WTl2   = (ushort_t*)take((size_t)sW2 * 2);
    ushort_t* WTr2   = (ushort_t*)take((size_t)sW2 * 2);
    float*    att1f  = (float*)take((size_t)satt1 * 4);
    float*    b1f    = (float*)take((size_t)sb1 * 4);
    float*    att2f  = (float*)take((size_t)satt2 * 4);
    float*    b2f    = (float*)take((size_t)sb2 * 4);
    float*    Wof    = (float*)take((size_t)sWo * 4);
    float*    bof    = (float*)take((size_t)sbo * 4);
    int*      deg    = (int*)take((size_t)N * sizeof(int));
    int*      offs   = (int*)take((size_t)(N + 1) * sizeof(int));
    int*      cursor = (int*)take((size_t)(N + 1) * sizeof(int));
    int*      s_src  = (int*)take((size_t)Etot * sizeof(int));
    ushort_t* h1     = (ushort_t*)take((size_t)N * 128 * sizeof(ushort_t));
    ushort_t* xl1b   = (ushort_t*)take((size_t)N * 128 * sizeof(ushort_t));
    ushort_t* xr1b   = (ushort_t*)take((size_t)N * 128 * sizeof(ushort_t));
    ushort_t* xl2b   = (ushort_t*)take((size_t)N * 512 * sizeof(ushort_t));
    ushort_t* xr2b   = (ushort_t*)take((size_t)N * 512 * sizeof(ushort_t));

    dim3 b256(256);
    k_detect<<<1, b256, 0, stream>>>((const uint_t*)x, ei, flags);
    k_cvt_x<<<(N * 128 + 255) / 256, b256, 0, stream>>>(x, xb, N * 128, flags);
    k_cvt_params<<<(sW2 + 255) / 256, b256, 0, stream>>>(
        Wl1, Wr1, att1, b1, Wl2, Wr2, att2, b2, Wo, bo,
        Wl1b, Wr1b, Wl2b, Wr2b, att1f, b1f, att2f, b2f, Wof, bof,
        sW1, sW2, satt1, sb1, satt2, sb2, sWo, sbo, flags);
    k_transpose2<<<(sW1 + 255) / 256, b256, 0, stream>>>(Wl1b, Wr1b, WTl1, WTr1, 128, 128);
    k_transpose2<<<(sW2 + 255) / 256, b256, 0, stream>>>(Wl2b, Wr2b, WTl2, WTr2, 128, 512);

    k_init<<<(N + 255) / 256, b256, 0, stream>>>(deg, N);
    k_count<<<(Etot + 255) / 256, b256, 0, stream>>>(ei, E_in, Etot, flags, deg);
    k_scan<<<1, 1024, 0, stream>>>(deg, offs, cursor, N);
    k_fill<<<(Etot + 255) / 256, b256, 0, stream>>>(ei, E_in, Etot, flags, cursor, s_src);

    dim3 g1((N / 16 + 3) / 4, 128 / 64);
    k_gemm<128><<<g1, b256, 0, stream>>>(xb, WTl1, xl1b, N);
    k_gemm<128><<<g1, b256, 0, stream>>>(xb, WTr1, xr1b, N);
    k_l1<<<(N + 3) / 4, b256, 0, stream>>>(xl1b, xr1b, offs, s_src, att1f, b1f, N, h1);

    dim3 g2((N / 16 + 3) / 4, 512 / 64);
    k_gemm<512><<<g2, b256, 0, stream>>>(h1, WTl2, xl2b, N);
    k_gemm<512><<<g2, b256, 0, stream>>>(h1, WTr2, xr2b, N);

    k_l2<<<N, b256, 0, stream>>>(xl2b, xr2b, offs, s_src, att2f, b2f, Wof, bof, N, flags, d_out);
}

// Round 5
// 668.361 us; speedup vs baseline: 1.8659x; 1.0382x over previous
//
#include <hip/hip_runtime.h>

#define NEG_SLOPE 0.2f

typedef unsigned short ushort_t;
typedef unsigned int uint_t;
typedef __attribute__((ext_vector_type(8))) short bf16x8;   // 8 bf16 in 4 VGPRs
typedef __attribute__((ext_vector_type(4))) float f32x4;

__device__ inline float bf2f(ushort_t u) { union { uint_t i; float f; } v; v.i = ((uint_t)u) << 16; return v.f; }
__device__ inline ushort_t f2bf(float f) {
    union { float f; uint_t u; } v; v.f = f;
    uint_t r = v.u + 0x7fffu + ((v.u >> 16) & 1u);
    return (ushort_t)(r >> 16);
}
__device__ inline float2 up2(uint_t w) { return make_float2(bf2f((ushort_t)(w & 0xFFFFu)), bf2f((ushort_t)(w >> 16))); }
// dtype-flexible loads (bf=1: buffer holds bf16; bf=0: fp32)
__device__ inline float ld_f(const void* p, size_t i, int bf) { return bf ? bf2f(((const ushort_t*)p)[i]) : ((const float*)p)[i]; }
__device__ inline ushort_t ld_b(const void* p, size_t i, int bf) { return bf ? ((const ushort_t*)p)[i] : f2bf(((const float*)p)[i]); }
// edge fetch with int64/int32 handling; self-loops appended at e >= E_in
__device__ inline void edge_sd(const int* __restrict__ ei, int e, int E_in, int i64, int& src, int& dst) {
    if (e < E_in) {
        if (i64) { src = ei[2 * (size_t)e]; dst = ei[2 * ((size_t)E_in + e)]; }
        else     { src = ei[e];             dst = ei[(size_t)E_in + e]; }
    } else { src = dst = e - E_in; }
}
// att-folded leaky dot contribution: att*leaky(m) == (0.6*att)*m + (0.4*att)*|m|
__device__ inline float dot2(float2 m, float2 a6, float2 a4, float e) {
    e = fmaf(a6.x, m.x, e); e = fmaf(a4.x, __builtin_fabsf(m.x), e);
    e = fmaf(a6.y, m.y, e); e = fmaf(a4.y, __builtin_fabsf(m.y), e);
    return e;
}

// ---------------- dtype detection ----------------
__global__ void k_detect(const uint_t* __restrict__ xw, const int* __restrict__ ei, int* flags) {
    __shared__ int cnt;
    if (threadIdx.x == 0) cnt = 0;
    __syncthreads();
    uint_t w = xw[threadIdx.x];
    int eb = (int)((w >> 7) & 0xFFu);
    if (eb >= 113 && eb <= 142) atomicAdd(&cnt, 1);
    __syncthreads();
    if (threadIdx.x == 0) {
        flags[0] = (cnt > 128) ? 1 : 0;
        int z = 0;
        #pragma unroll
        for (int i = 1; i < 16; i += 2) z += (ei[i] == 0) ? 1 : 0;
        flags[1] = (z == 8) ? 1 : 0;
    }
}

// ---------------- input normalization ----------------
__global__ void k_cvt_x(const void* __restrict__ x, ushort_t* __restrict__ xb, int n, const int* flags) {
    int i = blockIdx.x * blockDim.x + threadIdx.x;
    if (i < n) xb[i] = ld_b(x, i, flags[0]);
}

__global__ void k_cvt_params(const void* Wl1, const void* Wr1, const void* att1, const void* b1,
                             const void* Wl2, const void* Wr2, const void* att2, const void* b2,
                             const void* Wo, const void* bo,
                             ushort_t* Wl1b, ushort_t* Wr1b, ushort_t* Wl2b, ushort_t* Wr2b,
                             float* att1f, float* b1f, float* att2f, float* b2f, float* Wof, float* bof,
                             int sW1, int sW2, int satt1, int sb1, int satt2, int sb2, int sWo, int sbo,
                             const int* flags) {
    int i = blockIdx.x * blockDim.x + threadIdx.x;
    int bf = flags[0];
    if (i < sW1) { Wl1b[i] = ld_b(Wl1, i, bf); Wr1b[i] = ld_b(Wr1, i, bf); }
    if (i < sW2) { Wl2b[i] = ld_b(Wl2, i, bf); Wr2b[i] = ld_b(Wr2, i, bf); }
    if (i < satt1) att1f[i] = ld_f(att1, i, bf);
    if (i < sb1)   b1f[i]   = ld_f(b1, i, bf);
    if (i < satt2) att2f[i] = ld_f(att2, i, bf);
    if (i < sb2)   b2f[i]   = ld_f(b2, i, bf);
    if (i < sWo)   Wof[i]   = ld_f(Wo, i, bf);
    if (i < sbo)   bof[i]   = ld_f(bo, i, bf);
}

// transpose bf16 W[K][NOUT] -> WT[NOUT][K] for contiguous B-frag loads
__global__ void k_transpose2(const ushort_t* __restrict__ Wa, const ushort_t* __restrict__ Wb,
                             ushort_t* __restrict__ WTa, ushort_t* __restrict__ WTb,
                             int K, int NOUT) {
    int i = blockIdx.x * blockDim.x + threadIdx.x;
    if (i >= K * NOUT) return;
    int n = i >> 7, k = i & 127;          // K == 128 always here
    WTa[i] = Wa[(size_t)k * NOUT + n];
    WTb[i] = Wb[(size_t)k * NOUT + n];
}

// ---------------- init + CSR build over dst ----------------
__global__ void k_init(int* deg, int n) {
    int i = blockIdx.x * blockDim.x + threadIdx.x;
    if (i < n) deg[i] = 0;
}

__global__ void k_count(const int* __restrict__ ei, int E_in, int Etot, const int* flags, int* deg) {
    int e = blockIdx.x * blockDim.x + threadIdx.x;
    if (e >= Etot) return;
    int src, dst; edge_sd(ei, e, E_in, flags[1], src, dst);
    atomicAdd(&deg[dst], 1);
}

__global__ void k_scan(const int* __restrict__ deg, int* offs, int* cursor, int n) {
    __shared__ int sh[1024];
    int t = threadIdx.x;
    int chunk = (n + 1023) / 1024;
    int s = t * chunk, e = min(s + chunk, n);
    int local = 0;
    for (int i = s; i < e; i++) local += deg[i];
    sh[t] = local; __syncthreads();
    for (int off = 1; off < 1024; off <<= 1) {
        int v = (t >= off) ? sh[t - off] : 0;
        __syncthreads();
        sh[t] += v; __syncthreads();
    }
    int run = sh[t] - local;
    for (int i = s; i < e; i++) { offs[i] = run; cursor[i] = run; run += deg[i]; }
    if (e == n) offs[n] = run;
}

__global__ void k_fill(const int* __restrict__ ei, int E_in, int Etot, const int* flags,
                       int* cursor, int* s_src) {
    int e = blockIdx.x * blockDim.x + threadIdx.x;
    if (e >= Etot) return;
    int src, dst; edge_sd(ei, e, E_in, flags[1], src, dst);
    int p = atomicAdd(&cursor[dst], 1);
    s_src[p] = src;
}

// ------- MFMA GEMM: Y[M,NOUT](bf16) = X[M,128](bf16) @ W, B from WT[NOUT][128] -------
template <int NOUT>
__global__ __launch_bounds__(256) void k_gemm(const ushort_t* __restrict__ X,
                                              const ushort_t* __restrict__ WT,
                                              ushort_t* __restrict__ Y, int M) {
    const int lane = threadIdx.x & 63, wid = threadIdx.x >> 6;
    const int ntiles = M >> 4;
    int rt = blockIdx.x * 4 + wid;
    if (rt >= ntiles) return;
    const int colbase = blockIdx.y * 64;
    const int quad = lane >> 4, lo = lane & 15;

    bf16x8 bfr[4][4];  // B[k=quad*8+j][n=colbase+nt*16+lo] from WT: contiguous 16B
    #pragma unroll
    for (int nt = 0; nt < 4; nt++) {
        const ushort_t* wrow = WT + (size_t)(colbase + nt * 16 + lo) * 128 + quad * 8;
        #pragma unroll
        for (int kc = 0; kc < 4; kc++)
            bfr[nt][kc] = *(const bf16x8*)(wrow + kc * 32);
    }

    f32x4 acc[4];
    #pragma unroll
    for (int nt = 0; nt < 4; nt++) acc[nt] = (f32x4){0.f, 0.f, 0.f, 0.f};

    int r = rt * 16 + lo;
    const ushort_t* xrow = X + (size_t)r * 128 + quad * 8;
    #pragma unroll
    for (int kc = 0; kc < 4; kc++) {
        bf16x8 a = *(const bf16x8*)(xrow + kc * 32);
        #pragma unroll
        for (int nt = 0; nt < 4; nt++)
            acc[nt] = __builtin_amdgcn_mfma_f32_16x16x32_bf16(a, bfr[nt][kc], acc[nt], 0, 0, 0);
    }
    // C/D: col = lane&15, row = quad*4 + reg  [m89-verified]
    #pragma unroll
    for (int nt = 0; nt < 4; nt++) {
        int col = colbase + nt * 16 + lo;
        #pragma unroll
        for (int ri = 0; ri < 4; ri++) {
            int row = rt * 16 + quad * 4 + ri;
            Y[(size_t)row * NOUT + col] = f2bf(acc[nt][ri]);
        }
    }
}

// ======== layer 1 FUSED: slot-parallel exp-sum gather -> h1 (bf16) ========
// wave per node. 4 slots x 16 lanes; lane covers 8 ch (full 128-ch row per slot).
// head = (lane&15)>>2 (4 lanes/head). No max-tracking: |e| <~ 15 << 88, plain exp
// is exact; slots merge by plain butterfly adds.
__global__ __launch_bounds__(256) void k_l1(const ushort_t* __restrict__ xl,
                                            const ushort_t* __restrict__ xr,
                                            const int* __restrict__ offs,
                                            const int* __restrict__ s_src,
                                            const float* __restrict__ att,
                                            const float* __restrict__ b1,
                                            int n, ushort_t* __restrict__ h1) {
    int lane = threadIdx.x & 63, wid = threadIdx.x >> 6;
    int node = blockIdx.x * 4 + wid;
    if (node >= n) return;
    int slot = lane >> 4, sub = lane & 15;
    int chb = sub * 8;

    uint4 xw = *(const uint4*)(xr + (size_t)node * 128 + chb);
    float2 xv[4] = {up2(xw.x), up2(xw.y), up2(xw.z), up2(xw.w)};
    float2 a6[4], a4[4];
    #pragma unroll
    for (int j = 0; j < 4; j++) {
        float2 a = make_float2(att[chb + 2 * j], att[chb + 2 * j + 1]);
        a6[j] = make_float2(0.6f * a.x, 0.6f * a.y);
        a4[j] = make_float2(0.4f * a.x, 0.4f * a.y);
    }

    int o0 = offs[node], o1 = offs[node + 1];
    float s = 0.f;
    float2 acc[4] = {{0.f,0.f},{0.f,0.f},{0.f,0.f},{0.f,0.f}};

    int i = o0 + slot;
    uint4 w;
    if (i < o1) w = *(const uint4*)(xl + (size_t)s_src[i] * 128 + chb);
    while (i < o1) {
        uint4 wc = w;
        int in = i + 4;
        if (in < o1) w = *(const uint4*)(xl + (size_t)s_src[in] * 128 + chb);
        float2 v[4] = {up2(wc.x), up2(wc.y), up2(wc.z), up2(wc.w)};
        float e = 0.f;
        #pragma unroll
        for (int j = 0; j < 4; j++)
            e = dot2(make_float2(v[j].x + xv[j].x, v[j].y + xv[j].y), a6[j], a4[j], e);
        e += __shfl_xor(e, 1, 64);
        e += __shfl_xor(e, 2, 64);          // reduce over 4-lane head group
        float p = __expf(fminf(e, 80.f));
        s += p;
        #pragma unroll
        for (int j = 0; j < 4; j++) {
            acc[j].x = fmaf(p, v[j].x, acc[j].x);
            acc[j].y = fmaf(p, v[j].y, acc[j].y);
        }
        i = in;
    }
    // merge the 4 slots: plain butterfly adds (no rescale needed)
    #pragma unroll
    for (int off = 16; off <= 32; off <<= 1) {
        s += __shfl_xor(s, off, 64);
        #pragma unroll
        for (int j = 0; j < 4; j++) {
            acc[j].x += __shfl_xor(acc[j].x, off, 64);
            acc[j].y += __shfl_xor(acc[j].y, off, 64);
        }
    }
    if (slot == 0) {
        float inv = 1.f / s;
        uint_t pk[4];
        #pragma unroll
        for (int j = 0; j < 4; j++) {
            float r0 = fmaxf(fmaf(acc[j].x, inv, b1[chb + 2 * j]),     0.f);
            float r1 = fmaxf(fmaf(acc[j].y, inv, b1[chb + 2 * j + 1]), 0.f);
            pk[j] = (uint_t)f2bf(r0) | ((uint_t)f2bf(r1) << 16);
        }
        *(uint4*)(h1 + (size_t)node * 128 + chb) = make_uint4(pk[0], pk[1], pk[2], pk[3]);
    }
}

// ======== layer 2 FUSED: slot-parallel exp-sum + mean-heads + b2 + decoder ========
// block per node; wave = head. 4 slots x 16 lanes x 8 ch (head's 128 ch per slot).
__global__ __launch_bounds__(256) void k_l2(const ushort_t* __restrict__ xl,
                                            const ushort_t* __restrict__ xr,
                                            const int* __restrict__ offs,
                                            const int* __restrict__ s_src,
                                            const float* __restrict__ att,
                                            const float* __restrict__ b2,
                                            const float* __restrict__ Wo,
                                            const float* __restrict__ bo,
                                            int n, const int* flags, void* dout) {
    __shared__ float part[4][128];
    __shared__ float hbuf[128];
    int node = blockIdx.x;
    int h = threadIdx.x >> 6, lane = threadIdx.x & 63;
    int slot = lane >> 4, sub = lane & 15;
    int chb = sub * 8;
    size_t choff = (size_t)h * 128 + chb;

    uint4 xw = *(const uint4*)(xr + (size_t)node * 512 + choff);
    float2 xv[4] = {up2(xw.x), up2(xw.y), up2(xw.z), up2(xw.w)};
    float2 a6[4], a4[4];
    #pragma unroll
    for (int j = 0; j < 4; j++) {
        float2 a = make_float2(att[choff + 2 * j], att[choff + 2 * j + 1]);
        a6[j] = make_float2(0.6f * a.x, 0.6f * a.y);
        a4[j] = make_float2(0.4f * a.x, 0.4f * a.y);
    }

    int o0 = offs[node], o1 = offs[node + 1];
    float s = 0.f;
    float2 acc[4] = {{0.f,0.f},{0.f,0.f},{0.f,0.f},{0.f,0.f}};

    int i = o0 + slot;
    uint4 w;
    if (i < o1) w = *(const uint4*)(xl + (size_t)s_src[i] * 512 + choff);
    while (i < o1) {
        uint4 wc = w;
        int in = i + 4;
        if (in < o1) w = *(const uint4*)(xl + (size_t)s_src[in] * 512 + choff);
        float2 v[4] = {up2(wc.x), up2(wc.y), up2(wc.z), up2(wc.w)};
        float e = 0.f;
        #pragma unroll
        for (int j = 0; j < 4; j++)
            e = dot2(make_float2(v[j].x + xv[j].x, v[j].y + xv[j].y), a6[j], a4[j], e);
        #pragma unroll
        for (int o = 1; o < 16; o <<= 1) e += __shfl_xor(e, o, 64);  // 16-lane slot reduce
        float p = __expf(fminf(e, 80.f));
        s += p;
        #pragma unroll
        for (int j = 0; j < 4; j++) {
            acc[j].x = fmaf(p, v[j].x, acc[j].x);
            acc[j].y = fmaf(p, v[j].y, acc[j].y);
        }
        i = in;
    }
    // merge slots: plain butterfly adds
    #pragma unroll
    for (int off = 16; off <= 32; off <<= 1) {
        s += __shfl_xor(s, off, 64);
        #pragma unroll
        for (int j = 0; j < 4; j++) {
            acc[j].x += __shfl_xor(acc[j].x, off, 64);
            acc[j].y += __shfl_xor(acc[j].y, off, 64);
        }
    }
    if (slot == 0) {
        float inv = 1.f / s;
        #pragma unroll
        for (int j = 0; j < 4; j++) {
            part[h][chb + 2 * j]     = acc[j].x * inv;
            part[h][chb + 2 * j + 1] = acc[j].y * inv;
        }
    }
    __syncthreads();
    int t = threadIdx.x;
    int bf = flags[0];
    if (t < 128) {
        float hm = 0.25f * (part[0][t] + part[1][t] + part[2][t] + part[3][t]) + b2[t];
        hbuf[t] = hm;
        size_t oidx = (size_t)n * 2 + (size_t)node * 128 + t;
        if (bf) ((ushort_t*)dout)[oidx] = f2bf(hm);
        else    ((float*)dout)[oidx]    = hm;
    }
    __syncthreads();
    if (h < 2) {  // decoder
        float v = hbuf[lane] * Wo[lane * 2 + h] + hbuf[lane + 64] * Wo[(lane + 64) * 2 + h];
        #pragma unroll
        for (int o = 32; o > 0; o >>= 1) v += __shfl_xor(v, o, 64);
        if (lane == 0) {
            float r = v + bo[h];
            size_t oidx = (size_t)node * 2 + h;
            if (bf) ((ushort_t*)dout)[oidx] = f2bf(r);
            else    ((float*)dout)[oidx]    = r;
        }
    }
}

extern "C" void kernel_launch(void* const* d_in, const int* in_sizes, int n_in,
                              void* d_out, int out_size, void* d_ws, size_t ws_size,
                              hipStream_t stream) {
    const void* x    = d_in[0];
    const int*  ei   = (const int*)d_in[1];
    const void* Wl1  = d_in[2];
    const void* Wr1  = d_in[3];
    const void* att1 = d_in[4];
    const void* b1   = d_in[5];
    const void* Wl2  = d_in[6];
    const void* Wr2  = d_in[7];
    const void* att2 = d_in[8];
    const void* b2   = d_in[9];
    const void* Wo   = d_in[10];
    const void* bo   = d_in[11];

    const int N    = in_sizes[0] / 128;   // 50000
    const int E_in = in_sizes[1] / 2;     // 800000
    const int Etot = E_in + N;

    const int sW1 = in_sizes[2], sW2 = in_sizes[6];
    const int satt1 = in_sizes[4], sb1 = in_sizes[5];
    const int satt2 = in_sizes[8], sb2 = in_sizes[9];
    const int sWo = in_sizes[10], sbo = in_sizes[11];

    char* w = (char*)d_ws;
    size_t off = 0;
    auto take = [&](size_t bytes) -> void* {
        void* p = w + off;
        off += (bytes + 255) & ~(size_t)255;
        return p;
    };
    int*      flags  = (int*)take(256);
    ushort_t* xb     = (ushort_t*)take((size_t)N * 128 * sizeof(ushort_t));
    ushort_t* Wl1b   = (ushort_t*)take((size_t)sW1 * 2);
    ushort_t* Wr1b   = (ushort_t*)take((size_t)sW1 * 2);
    ushort_t* Wl2b   = (ushort_t*)take((size_t)sW2 * 2);
    ushort_t* Wr2b   = (ushort_t*)take((size_t)sW2 * 2);
    ushort_t* WTl1   = (ushort_t*)take((size_t)sW1 * 2);
    ushort_t* WTr1   = (ushort_t*)take((size_t)sW1 * 2);
    ushort_t* WTl2   = (ushort_t*)take((size_t)sW2 * 2);
    ushort_t* WTr2   = (ushort_t*)take((size_t)sW2 * 2);
    float*    att1f  = (float*)take((size_t)satt1 * 4);
    float*    b1f    = (float*)take((size_t)sb1 * 4);
    float*    att2f  = (float*)take((size_t)satt2 * 4);
    float*    b2f    = (float*)take((size_t)sb2 * 4);
    float*    Wof    = (float*)take((size_t)sWo * 4);
    float*    bof    = (float*)take((size_t)sbo * 4);
    int*      deg    = (int*)take((size_t)N * sizeof(int));
    int*      offs   = (int*)take((size_t)(N + 1) * sizeof(int));
    int*      cursor = (int*)take((size_t)(N + 1) * sizeof(int));
    int*      s_src  = (int*)take((size_t)Etot * sizeof(int));
    ushort_t* h1     = (ushort_t*)take((size_t)N * 128 * sizeof(ushort_t));
    ushort_t* xl1b   = (ushort_t*)take((size_t)N * 128 * sizeof(ushort_t));
    ushort_t* xr1b   = (ushort_t*)take((size_t)N * 128 * sizeof(ushort_t));
    ushort_t* xl2b   = (ushort_t*)take((size_t)N * 512 * sizeof(ushort_t));
    ushort_t* xr2b   = (ushort_t*)take((size_t)N * 512 * sizeof(ushort_t));

    dim3 b256(256);
    k_detect<<<1, b256, 0, stream>>>((const uint_t*)x, ei, flags);
    k_cvt_x<<<(N * 128 + 255) / 256, b256, 0, stream>>>(x, xb, N * 128, flags);
    k_cvt_params<<<(sW2 + 255) / 256, b256, 0, stream>>>(
        Wl1, Wr1, att1, b1, Wl2, Wr2, att2, b2, Wo, bo,
        Wl1b, Wr1b, Wl2b, Wr2b, att1f, b1f, att2f, b2f, Wof, bof,
        sW1, sW2, satt1, sb1, satt2, sb2, sWo, sbo, flags);
    k_transpose2<<<(sW1 + 255) / 256, b256, 0, stream>>>(Wl1b, Wr1b, WTl1, WTr1, 128, 128);
    k_transpose2<<<(sW2 + 255) / 256, b256, 0, stream>>>(Wl2b, Wr2b, WTl2, WTr2, 128, 512);

    k_init<<<(N + 255) / 256, b256, 0, stream>>>(deg, N);
    k_count<<<(Etot + 255) / 256, b256, 0, stream>>>(ei, E_in, Etot, flags, deg);
    k_scan<<<1, 1024, 0, stream>>>(deg, offs, cursor, N);
    k_fill<<<(Etot + 255) / 256, b256, 0, stream>>>(ei, E_in, Etot, flags, cursor, s_src);

    dim3 g1((N / 16 + 3) / 4, 128 / 64);
    k_gemm<128><<<g1, b256, 0, stream>>>(xb, WTl1, xl1b, N);
    k_gemm<128><<<g1, b256, 0, stream>>>(xb, WTr1, xr1b, N);
    k_l1<<<(N + 3) / 4, b256, 0, stream>>>(xl1b, xr1b, offs, s_src, att1f, b1f, N, h1);

    dim3 g2((N / 16 + 3) / 4, 512 / 64);
    k_gemm<512><<<g2, b256, 0, stream>>>(h1, WTl2, xl2b, N);
    k_gemm<512><<<g2, b256, 0, stream>>>(h1, WTr2, xr2b, N);

    k_l2<<<N, b256, 0, stream>>>(xl2b, xr2b, offs, s_src, att2f, b2f, Wof, bof, N, flags, d_out);
}

// Round 6
// 569.779 us; speedup vs baseline: 2.1887x; 1.1730x over previous
//
#include <hip/hip_runtime.h>

#define NEG_SLOPE 0.2f

typedef unsigned short ushort_t;
typedef unsigned int uint_t;
typedef __attribute__((ext_vector_type(8))) short bf16x8;   // 8 bf16 in 4 VGPRs
typedef __attribute__((ext_vector_type(4))) float f32x4;

__device__ inline float bf2f(ushort_t u) { union { uint_t i; float f; } v; v.i = ((uint_t)u) << 16; return v.f; }
__device__ inline ushort_t f2bf(float f) {
    union { float f; uint_t u; } v; v.f = f;
    uint_t r = v.u + 0x7fffu + ((v.u >> 16) & 1u);
    return (ushort_t)(r >> 16);
}
__device__ inline float2 up2(uint_t w) { return make_float2(bf2f((ushort_t)(w & 0xFFFFu)), bf2f((ushort_t)(w >> 16))); }
// dtype-flexible loads (bf=1: buffer holds bf16; bf=0: fp32)
__device__ inline float ld_f(const void* p, size_t i, int bf) { return bf ? bf2f(((const ushort_t*)p)[i]) : ((const float*)p)[i]; }
__device__ inline ushort_t ld_b(const void* p, size_t i, int bf) { return bf ? ((const ushort_t*)p)[i] : f2bf(((const float*)p)[i]); }
// edge fetch with int64/int32 handling; self-loops appended at e >= E_in
__device__ inline void edge_sd(const int* __restrict__ ei, int e, int E_in, int i64, int& src, int& dst) {
    if (e < E_in) {
        if (i64) { src = ei[2 * (size_t)e]; dst = ei[2 * ((size_t)E_in + e)]; }
        else     { src = ei[e];             dst = ei[(size_t)E_in + e]; }
    } else { src = dst = e - E_in; }
}
// att-folded leaky dot contribution: att*leaky(m) == (0.6*att)*m + (0.4*att)*|m|
__device__ inline float dot2(float2 m, float2 a6, float2 a4, float e) {
    e = fmaf(a6.x, m.x, e); e = fmaf(a4.x, __builtin_fabsf(m.x), e);
    e = fmaf(a6.y, m.y, e); e = fmaf(a4.y, __builtin_fabsf(m.y), e);
    return e;
}

// ---------------- dtype detection ----------------
__global__ void k_detect(const uint_t* __restrict__ xw, const int* __restrict__ ei, int* flags) {
    __shared__ int cnt;
    if (threadIdx.x == 0) cnt = 0;
    __syncthreads();
    uint_t w = xw[threadIdx.x];
    int eb = (int)((w >> 7) & 0xFFu);
    if (eb >= 113 && eb <= 142) atomicAdd(&cnt, 1);
    __syncthreads();
    if (threadIdx.x == 0) {
        flags[0] = (cnt > 128) ? 1 : 0;
        int z = 0;
        #pragma unroll
        for (int i = 1; i < 16; i += 2) z += (ei[i] == 0) ? 1 : 0;
        flags[1] = (z == 8) ? 1 : 0;
    }
}

// ---------------- input normalization ----------------
__global__ void k_cvt_x(const void* __restrict__ x, ushort_t* __restrict__ xb, int n, const int* flags) {
    int i = blockIdx.x * blockDim.x + threadIdx.x;
    if (i < n) xb[i] = ld_b(x, i, flags[0]);
}

__global__ void k_cvt_params(const void* Wl1, const void* Wr1, const void* att1, const void* b1,
                             const void* Wl2, const void* Wr2, const void* att2, const void* b2,
                             const void* Wo, const void* bo,
                             ushort_t* Wl1b, ushort_t* Wr1b, ushort_t* Wl2b, ushort_t* Wr2b,
                             float* att1f, float* b1f, float* att2f, float* b2f, float* Wof, float* bof,
                             int sW1, int sW2, int satt1, int sb1, int satt2, int sb2, int sWo, int sbo,
                             const int* flags) {
    int i = blockIdx.x * blockDim.x + threadIdx.x;
    int bf = flags[0];
    if (i < sW1) { Wl1b[i] = ld_b(Wl1, i, bf); Wr1b[i] = ld_b(Wr1, i, bf); }
    if (i < sW2) { Wl2b[i] = ld_b(Wl2, i, bf); Wr2b[i] = ld_b(Wr2, i, bf); }
    if (i < satt1) att1f[i] = ld_f(att1, i, bf);
    if (i < sb1)   b1f[i]   = ld_f(b1, i, bf);
    if (i < satt2) att2f[i] = ld_f(att2, i, bf);
    if (i < sb2)   b2f[i]   = ld_f(b2, i, bf);
    if (i < sWo)   Wof[i]   = ld_f(Wo, i, bf);
    if (i < sbo)   bof[i]   = ld_f(bo, i, bf);
}

// transpose bf16 W[K][NOUT] -> WT[NOUT][K] for contiguous B-frag loads
__global__ void k_transpose2(const ushort_t* __restrict__ Wa, const ushort_t* __restrict__ Wb,
                             ushort_t* __restrict__ WTa, ushort_t* __restrict__ WTb,
                             int K, int NOUT) {
    int i = blockIdx.x * blockDim.x + threadIdx.x;
    if (i >= K * NOUT) return;
    int n = i >> 7, k = i & 127;          // K == 128 always here
    WTa[i] = Wa[(size_t)k * NOUT + n];
    WTb[i] = Wb[(size_t)k * NOUT + n];
}

// ---------------- init + CSR build over dst ----------------
__global__ void k_init(int* deg, int n) {
    int i = blockIdx.x * blockDim.x + threadIdx.x;
    if (i < n) deg[i] = 0;
}

__global__ void k_count(const int* __restrict__ ei, int E_in, int Etot, const int* flags, int* deg) {
    int e = blockIdx.x * blockDim.x + threadIdx.x;
    if (e >= Etot) return;
    int dst;
    if (e < E_in) dst = flags[1] ? ei[2 * ((size_t)E_in + e)] : ei[(size_t)E_in + e];
    else          dst = e - E_in;
    atomicAdd(&deg[dst], 1);
}

// -------- hierarchical exclusive scan: A (block scan) -> B (scan of sums) -> C (add) ----
__global__ __launch_bounds__(256) void k_scanA(const int* __restrict__ deg, int* offs, int* bsum, int n) {
    __shared__ int sh[256];
    int t = threadIdx.x;
    int i = blockIdx.x * 256 + t;
    int v = (i < n) ? deg[i] : 0;
    sh[t] = v; __syncthreads();
    #pragma unroll
    for (int off = 1; off < 256; off <<= 1) {
        int u = (t >= off) ? sh[t - off] : 0;
        __syncthreads();
        sh[t] += u; __syncthreads();
    }
    if (i < n) offs[i] = sh[t] - v;            // exclusive, block-local
    if (t == 255) bsum[blockIdx.x] = sh[255];  // block total
}

__global__ __launch_bounds__(256) void k_scanB(int* bsum, int* offs, int nb, int n) {
    __shared__ int sh[256];
    int t = threadIdx.x;
    int v = (t < nb) ? bsum[t] : 0;
    sh[t] = v; __syncthreads();
    #pragma unroll
    for (int off = 1; off < 256; off <<= 1) {
        int u = (t >= off) ? sh[t - off] : 0;
        __syncthreads();
        sh[t] += u; __syncthreads();
    }
    if (t < nb) bsum[t] = sh[t] - v;           // exclusive scan of block sums
    if (t == 255) offs[n] = sh[255];           // grand total
}

__global__ __launch_bounds__(256) void k_scanC(int* offs, int* cursor, const int* __restrict__ bsum, int n) {
    int i = blockIdx.x * 256 + threadIdx.x;
    if (i >= n) return;
    int o = offs[i] + bsum[blockIdx.x];
    offs[i] = o; cursor[i] = o;
}

__global__ void k_fill(const int* __restrict__ ei, int E_in, int Etot, const int* flags,
                       int* cursor, int* s_src) {
    int e = blockIdx.x * blockDim.x + threadIdx.x;
    if (e >= Etot) return;
    int src, dst; edge_sd(ei, e, E_in, flags[1], src, dst);
    int p = atomicAdd(&cursor[dst], 1);
    s_src[p] = src;
}

// ---- fused dual MFMA GEMM: Yl/Yr[M,NOUT] = X[M,128] @ {WTl,WTr}; A-frags loaded once ----
template <int NOUT>
__global__ __launch_bounds__(256) void k_gemm2(const ushort_t* __restrict__ X,
                                               const ushort_t* __restrict__ WTl,
                                               const ushort_t* __restrict__ WTr,
                                               ushort_t* __restrict__ Yl,
                                               ushort_t* __restrict__ Yr, int M) {
    const int lane = threadIdx.x & 63, wid = threadIdx.x >> 6;
    int rt = blockIdx.x * 4 + wid;
    if (rt >= (M >> 4)) return;
    const int quad = lane >> 4, lo = lane & 15;

    // A fragments once per wave: A[m=lo][k=quad*8+j]
    const ushort_t* xrow = X + (size_t)(rt * 16 + lo) * 128 + quad * 8;
    bf16x8 afr[4];
    #pragma unroll
    for (int kc = 0; kc < 4; kc++) afr[kc] = *(const bf16x8*)(xrow + kc * 32);

    #pragma unroll
    for (int g = 0; g < NOUT / 64; g++) {
        #pragma unroll
        for (int side = 0; side < 2; side++) {
            const ushort_t* WT = side ? WTr : WTl;
            ushort_t*       Y  = side ? Yr  : Yl;
            f32x4 acc[4];
            #pragma unroll
            for (int nt = 0; nt < 4; nt++) acc[nt] = (f32x4){0.f, 0.f, 0.f, 0.f};
            #pragma unroll
            for (int nt = 0; nt < 4; nt++) {
                const ushort_t* wrow = WT + (size_t)(g * 64 + nt * 16 + lo) * 128 + quad * 8;
                #pragma unroll
                for (int kc = 0; kc < 4; kc++) {
                    bf16x8 b = *(const bf16x8*)(wrow + kc * 32);
                    acc[nt] = __builtin_amdgcn_mfma_f32_16x16x32_bf16(afr[kc], b, acc[nt], 0, 0, 0);
                }
            }
            // C/D: col = lane&15, row = quad*4 + reg  [m89-verified]
            #pragma unroll
            for (int nt = 0; nt < 4; nt++) {
                int col = g * 64 + nt * 16 + lo;
                #pragma unroll
                for (int ri = 0; ri < 4; ri++) {
                    int row = rt * 16 + quad * 4 + ri;
                    Y[(size_t)row * NOUT + col] = f2bf(acc[nt][ri]);
                }
            }
        }
    }
}

// ======== layer 1 FUSED: slot-parallel exp-sum gather -> h1 (bf16) ========
// wave per node. 4 slots x 16 lanes; lane covers 8 ch; head = (lane&15)>>2.
__global__ __launch_bounds__(256) void k_l1(const ushort_t* __restrict__ xl,
                                            const ushort_t* __restrict__ xr,
                                            const int* __restrict__ offs,
                                            const int* __restrict__ s_src,
                                            const float* __restrict__ att,
                                            const float* __restrict__ b1,
                                            int n, ushort_t* __restrict__ h1) {
    int lane = threadIdx.x & 63, wid = threadIdx.x >> 6;
    int node = blockIdx.x * 4 + wid;
    if (node >= n) return;
    int slot = lane >> 4, sub = lane & 15;
    int chb = sub * 8;

    uint4 xw = *(const uint4*)(xr + (size_t)node * 128 + chb);
    float2 xv[4] = {up2(xw.x), up2(xw.y), up2(xw.z), up2(xw.w)};
    float2 a6[4], a4[4];
    #pragma unroll
    for (int j = 0; j < 4; j++) {
        float2 a = make_float2(att[chb + 2 * j], att[chb + 2 * j + 1]);
        a6[j] = make_float2(0.6f * a.x, 0.6f * a.y);
        a4[j] = make_float2(0.4f * a.x, 0.4f * a.y);
    }

    int o0 = offs[node], o1 = offs[node + 1];
    float s = 0.f;
    float2 acc[4] = {{0.f,0.f},{0.f,0.f},{0.f,0.f},{0.f,0.f}};

    int i = o0 + slot;
    uint4 w;
    if (i < o1) w = *(const uint4*)(xl + (size_t)s_src[i] * 128 + chb);
    while (i < o1) {
        uint4 wc = w;
        int in = i + 4;
        if (in < o1) w = *(const uint4*)(xl + (size_t)s_src[in] * 128 + chb);
        float2 v[4] = {up2(wc.x), up2(wc.y), up2(wc.z), up2(wc.w)};
        float e = 0.f;
        #pragma unroll
        for (int j = 0; j < 4; j++)
            e = dot2(make_float2(v[j].x + xv[j].x, v[j].y + xv[j].y), a6[j], a4[j], e);
        e += __shfl_xor(e, 1, 64);
        e += __shfl_xor(e, 2, 64);          // reduce over 4-lane head group
        float p = __expf(fminf(e, 80.f));
        s += p;
        #pragma unroll
        for (int j = 0; j < 4; j++) {
            acc[j].x = fmaf(p, v[j].x, acc[j].x);
            acc[j].y = fmaf(p, v[j].y, acc[j].y);
        }
        i = in;
    }
    // merge the 4 slots: plain butterfly adds
    #pragma unroll
    for (int off = 16; off <= 32; off <<= 1) {
        s += __shfl_xor(s, off, 64);
        #pragma unroll
        for (int j = 0; j < 4; j++) {
            acc[j].x += __shfl_xor(acc[j].x, off, 64);
            acc[j].y += __shfl_xor(acc[j].y, off, 64);
        }
    }
    if (slot == 0) {
        float inv = 1.f / s;
        uint_t pk[4];
        #pragma unroll
        for (int j = 0; j < 4; j++) {
            float r0 = fmaxf(fmaf(acc[j].x, inv, b1[chb + 2 * j]),     0.f);
            float r1 = fmaxf(fmaf(acc[j].y, inv, b1[chb + 2 * j + 1]), 0.f);
            pk[j] = (uint_t)f2bf(r0) | ((uint_t)f2bf(r1) << 16);
        }
        *(uint4*)(h1 + (size_t)node * 128 + chb) = make_uint4(pk[0], pk[1], pk[2], pk[3]);
    }
}

// ======== layer 2 FUSED: slot-parallel exp-sum + mean-heads + b2 + decoder ========
// block per node; wave = head. 4 slots x 16 lanes x 8 ch.
__global__ __launch_bounds__(256) void k_l2(const ushort_t* __restrict__ xl,
                                            const ushort_t* __restrict__ xr,
                                            const int* __restrict__ offs,
                                            const int* __restrict__ s_src,
                                            const float* __restrict__ att,
                                            const float* __restrict__ b2,
                                            const float* __restrict__ Wo,
                                            const float* __restrict__ bo,
                                            int n, const int* flags, void* dout) {
    __shared__ float part[4][128];
    __shared__ float hbuf[128];
    int node = blockIdx.x;
    int h = threadIdx.x >> 6, lane = threadIdx.x & 63;
    int slot = lane >> 4, sub = lane & 15;
    int chb = sub * 8;
    size_t choff = (size_t)h * 128 + chb;

    uint4 xw = *(const uint4*)(xr + (size_t)node * 512 + choff);
    float2 xv[4] = {up2(xw.x), up2(xw.y), up2(xw.z), up2(xw.w)};
    float2 a6[4], a4[4];
    #pragma unroll
    for (int j = 0; j < 4; j++) {
        float2 a = make_float2(att[choff + 2 * j], att[choff + 2 * j + 1]);
        a6[j] = make_float2(0.6f * a.x, 0.6f * a.y);
        a4[j] = make_float2(0.4f * a.x, 0.4f * a.y);
    }

    int o0 = offs[node], o1 = offs[node + 1];
    float s = 0.f;
    float2 acc[4] = {{0.f,0.f},{0.f,0.f},{0.f,0.f},{0.f,0.f}};

    int i = o0 + slot;
    uint4 w;
    if (i < o1) w = *(const uint4*)(xl + (size_t)s_src[i] * 512 + choff);
    while (i < o1) {
        uint4 wc = w;
        int in = i + 4;
        if (in < o1) w = *(const uint4*)(xl + (size_t)s_src[in] * 512 + choff);
        float2 v[4] = {up2(wc.x), up2(wc.y), up2(wc.z), up2(wc.w)};
        float e = 0.f;
        #pragma unroll
        for (int j = 0; j < 4; j++)
            e = dot2(make_float2(v[j].x + xv[j].x, v[j].y + xv[j].y), a6[j], a4[j], e);
        #pragma unroll
        for (int o = 1; o < 16; o <<= 1) e += __shfl_xor(e, o, 64);  // 16-lane slot reduce
        float p = __expf(fminf(e, 80.f));
        s += p;
        #pragma unroll
        for (int j = 0; j < 4; j++) {
            acc[j].x = fmaf(p, v[j].x, acc[j].x);
            acc[j].y = fmaf(p, v[j].y, acc[j].y);
        }
        i = in;
    }
    // merge slots: plain butterfly adds
    #pragma unroll
    for (int off = 16; off <= 32; off <<= 1) {
        s += __shfl_xor(s, off, 64);
        #pragma unroll
        for (int j = 0; j < 4; j++) {
            acc[j].x += __shfl_xor(acc[j].x, off, 64);
            acc[j].y += __shfl_xor(acc[j].y, off, 64);
        }
    }
    if (slot == 0) {
        float inv = 1.f / s;
        #pragma unroll
        for (int j = 0; j < 4; j++) {
            part[h][chb + 2 * j]     = acc[j].x * inv;
            part[h][chb + 2 * j + 1] = acc[j].y * inv;
        }
    }
    __syncthreads();
    int t = threadIdx.x;
    int bf = flags[0];
    if (t < 128) {
        float hm = 0.25f * (part[0][t] + part[1][t] + part[2][t] + part[3][t]) + b2[t];
        hbuf[t] = hm;
        size_t oidx = (size_t)n * 2 + (size_t)node * 128 + t;
        if (bf) ((ushort_t*)dout)[oidx] = f2bf(hm);
        else    ((float*)dout)[oidx]    = hm;
    }
    __syncthreads();
    if (h < 2) {  // decoder
        float v = hbuf[lane] * Wo[lane * 2 + h] + hbuf[lane + 64] * Wo[(lane + 64) * 2 + h];
        #pragma unroll
        for (int o = 32; o > 0; o >>= 1) v += __shfl_xor(v, o, 64);
        if (lane == 0) {
            float r = v + bo[h];
            size_t oidx = (size_t)node * 2 + h;
            if (bf) ((ushort_t*)dout)[oidx] = f2bf(r);
            else    ((float*)dout)[oidx]    = r;
        }
    }
}

extern "C" void kernel_launch(void* const* d_in, const int* in_sizes, int n_in,
                              void* d_out, int out_size, void* d_ws, size_t ws_size,
                              hipStream_t stream) {
    const void* x    = d_in[0];
    const int*  ei   = (const int*)d_in[1];
    const void* Wl1  = d_in[2];
    const void* Wr1  = d_in[3];
    const void* att1 = d_in[4];
    const void* b1   = d_in[5];
    const void* Wl2  = d_in[6];
    const void* Wr2  = d_in[7];
    const void* att2 = d_in[8];
    const void* b2   = d_in[9];
    const void* Wo   = d_in[10];
    const void* bo   = d_in[11];

    const int N    = in_sizes[0] / 128;   // 50000
    const int E_in = in_sizes[1] / 2;     // 800000
    const int Etot = E_in + N;

    const int sW1 = in_sizes[2], sW2 = in_sizes[6];
    const int satt1 = in_sizes[4], sb1 = in_sizes[5];
    const int satt2 = in_sizes[8], sb2 = in_sizes[9];
    const int sWo = in_sizes[10], sbo = in_sizes[11];

    char* w = (char*)d_ws;
    size_t off = 0;
    auto take = [&](size_t bytes) -> void* {
        void* p = w + off;
        off += (bytes + 255) & ~(size_t)255;
        return p;
    };
    int*      flags  = (int*)take(256);
    ushort_t* xb     = (ushort_t*)take((size_t)N * 128 * sizeof(ushort_t));
    ushort_t* Wl1b   = (ushort_t*)take((size_t)sW1 * 2);
    ushort_t* Wr1b   = (ushort_t*)take((size_t)sW1 * 2);
    ushort_t* Wl2b   = (ushort_t*)take((size_t)sW2 * 2);
    ushort_t* Wr2b   = (ushort_t*)take((size_t)sW2 * 2);
    ushort_t* WTl1   = (ushort_t*)take((size_t)sW1 * 2);
    ushort_t* WTr1   = (ushort_t*)take((size_t)sW1 * 2);
    ushort_t* WTl2   = (ushort_t*)take((size_t)sW2 * 2);
    ushort_t* WTr2   = (ushort_t*)take((size_t)sW2 * 2);
    float*    att1f  = (float*)take((size_t)satt1 * 4);
    float*    b1f    = (float*)take((size_t)sb1 * 4);
    float*    att2f  = (float*)take((size_t)satt2 * 4);
    float*    b2f    = (float*)take((size_t)sb2 * 4);
    float*    Wof    = (float*)take((size_t)sWo * 4);
    float*    bof    = (float*)take((size_t)sbo * 4);
    int*      deg    = (int*)take((size_t)N * sizeof(int));
    int*      offs   = (int*)take((size_t)(N + 1) * sizeof(int));
    int*      cursor = (int*)take((size_t)(N + 1) * sizeof(int));
    int*      bsum   = (int*)take(1024);
    int*      s_src  = (int*)take((size_t)Etot * sizeof(int));
    ushort_t* h1     = (ushort_t*)take((size_t)N * 128 * sizeof(ushort_t));
    ushort_t* xl1b   = (ushort_t*)take((size_t)N * 128 * sizeof(ushort_t));
    ushort_t* xr1b   = (ushort_t*)take((size_t)N * 128 * sizeof(ushort_t));
    ushort_t* xl2b   = (ushort_t*)take((size_t)N * 512 * sizeof(ushort_t));
    ushort_t* xr2b   = (ushort_t*)take((size_t)N * 512 * sizeof(ushort_t));

    dim3 b256(256);
    const int nb = (N + 255) / 256;       // 196 scan blocks

    k_detect<<<1, b256, 0, stream>>>((const uint_t*)x, ei, flags);
    k_cvt_x<<<(N * 128 + 255) / 256, b256, 0, stream>>>(x, xb, N * 128, flags);
    k_cvt_params<<<(sW2 + 255) / 256, b256, 0, stream>>>(
        Wl1, Wr1, att1, b1, Wl2, Wr2, att2, b2, Wo, bo,
        Wl1b, Wr1b, Wl2b, Wr2b, att1f, b1f, att2f, b2f, Wof, bof,
        sW1, sW2, satt1, sb1, satt2, sb2, sWo, sbo, flags);
    k_transpose2<<<(sW1 + 255) / 256, b256, 0, stream>>>(Wl1b, Wr1b, WTl1, WTr1, 128, 128);
    k_transpose2<<<(sW2 + 255) / 256, b256, 0, stream>>>(Wl2b, Wr2b, WTl2, WTr2, 128, 512);

    k_init<<<nb, b256, 0, stream>>>(deg, N);
    k_count<<<(Etot + 255) / 256, b256, 0, stream>>>(ei, E_in, Etot, flags, deg);
    k_scanA<<<nb, b256, 0, stream>>>(deg, offs, bsum, N);
    k_scanB<<<1, b256, 0, stream>>>(bsum, offs, nb, N);
    k_scanC<<<nb, b256, 0, stream>>>(offs, cursor, bsum, N);
    k_fill<<<(Etot + 255) / 256, b256, 0, stream>>>(ei, E_in, Etot, flags, cursor, s_src);

    dim3 gg((N / 16 + 3) / 4);
    k_gemm2<128><<<gg, b256, 0, stream>>>(xb, WTl1, WTr1, xl1b, xr1b, N);
    k_l1<<<(N + 3) / 4, b256, 0, stream>>>(xl1b, xr1b, offs, s_src, att1f, b1f, N, h1);

    k_gemm2<512><<<gg, b256, 0, stream>>>(h1, WTl2, WTr2, xl2b, xr2b, N);

    k_l2<<<N, b256, 0, stream>>>(xl2b, xr2b, offs, s_src, att2f, b2f, Wof, bof, N, flags, d_out);
}